// Round 24
// baseline (340.690 us; speedup 1.0000x reference)
//
#include <hip/hip_runtime.h>
#include <math.h>

#define N_DST   32768
#define N_EDGE  524288
#define LN_EPS  1e-5f

typedef __attribute__((ext_vector_type(8))) short short8b;   // 8 bf16 (4 VGPR)
typedef __attribute__((ext_vector_type(4))) float f32x4;

static __device__ __forceinline__ unsigned short f2bf(float f) {
    unsigned u = __float_as_uint(f);
    u += 0x7fff + ((u >> 16) & 1);          // round-to-nearest-even
    return (unsigned short)(u >> 16);
}

// ---------- prep: zq, wout^T, Bv pack (block-diag V weights -> MFMA B-frag order) ----------
__global__ void k_prep(const float* __restrict__ wkv_w, const float* __restrict__ wq_w,
                       const float* __restrict__ wq_b, const float* __restrict__ time_b,
                       const float* __restrict__ wout_w,
                       float* __restrict__ zq, float* __restrict__ wout_t,
                       unsigned short* __restrict__ Bv) {
    int idx = blockIdx.x * 256 + threadIdx.x;
    if (idx < 100) {
        float acc = wq_b[idx];
        for (int j = 0; j < 100; ++j)
            acc += cosf(time_b[j]) * wq_w[idx * 200 + 100 + j];
        zq[idx] = acc;
    } else if (idx < 20100) {
        int r = idx - 100;                      // wout_t[i][o] = wout_w[o][i]
        wout_t[r] = wout_w[(size_t)(r % 100) * 200 + r / 100];
    } else if (idx < 95364) {
        int r2 = idx - 20100;
        int jj = r2 & 7, l = (r2 >> 3) & 63, nf = (r2 >> 9) % 7, kc = r2 / 3584;
        int j = kc * 32 + ((l >> 4) << 3) + jj;
        int o = nf * 16 + (l & 15);
        float v = (j < 600 && o < 100 && (j / 300 == o / 50))
                  ? wkv_w[(size_t)(100 + o) * 300 + (j % 300)] : 0.f;
        Bv[r2] = f2bf(v);
    }
}

// ---------- A2/C2: fold Q-projection into QW map (j<600: X dims; j=600+h: K-bias dot) ----------
__global__ void k_precomp(const float* __restrict__ wq_w, const float* __restrict__ wkv_w,
                          const float* __restrict__ wkv_b, const float* __restrict__ zq,
                          float* __restrict__ A2, float* __restrict__ C2) {
    int idx = blockIdx.x * 256 + threadIdx.x;
    if (idx < 60200) {
        int i = idx / 602, j = idx % 602;
        float acc = 0.f;
        if (j < 600) {
            int h = j / 300, cc = j % 300;
            const float* __restrict__ wq = wq_w + (size_t)(h * 50) * 200 + i;
            const float* __restrict__ wk = wkv_w + (size_t)(h * 50) * 300 + cc;
            #pragma unroll 10
            for (int d = 0; d < 50; ++d)
                acc = fmaf(wq[(size_t)d * 200], wk[(size_t)d * 300], acc);
        } else {
            int h = j - 600;
            const float* __restrict__ wq = wq_w + (size_t)(h * 50) * 200 + i;
            for (int d = 0; d < 50; ++d)
                acc = fmaf(wq[(size_t)d * 200], wkv_b[h * 50 + d], acc);
        }
        A2[idx] = acc;
    } else if (idx < 60802) {
        int j = idx - 60200;
        float acc = 0.f;
        if (j < 600) {
            int h = j / 300, cc = j % 300;
            for (int d = 0; d < 50; ++d)
                acc = fmaf(zq[h * 50 + d], wkv_w[(size_t)(h * 50 + d) * 300 + cc], acc);
        } else {
            int h = j - 600;
            for (int d = 0; d < 50; ++d)
                acc = fmaf(zq[h * 50 + d], wkv_b[h * 50 + d], acc);
        }
        C2[j] = acc;
    }
}

// ---------- Bq pack: A2 -> MFMA B-frag order ----------
__global__ void k_pack(const float* __restrict__ A2, unsigned short* __restrict__ Bq) {
    int idx = blockIdx.x * 256 + threadIdx.x;
    if (idx >= 77824) return;
    int jj = idx & 7, l = (idx >> 3) & 63, nf = (idx >> 9) % 19, kcp = idx / 9728;
    int kc = kcp & 3, p = kcp >> 2;
    int k = kc * 32 + ((l >> 4) << 3) + jj;
    int c = p * 304 + nf * 16 + (l & 15);
    float v = (k < 100 && c < 602) ? A2[(size_t)k * 602 + c] : 0.f;
    Bq[idx] = f2bf(v);
}

// ---------- CSR offsets via binary search over sorted edge_dst ----------
__global__ void k_offsets(const int* __restrict__ dst, int* __restrict__ off) {
    int n = blockIdx.x * 256 + threadIdx.x;
    if (n > N_DST) return;
    int lo = 0, hi = N_EDGE;
    while (lo < hi) {
        int mid = (lo + hi) >> 1;
        if (dst[mid] < n) lo = mid + 1; else hi = mid;
    }
    off[n] = lo;
}

// ---------- k_qw (MFMA): QW[32768x602] = dst_h @ A2 + C2 ----------
__global__ __launch_bounds__(256, 1) void k_qw(
        const float* __restrict__ dst_h, const unsigned short* __restrict__ Bq,
        const float* __restrict__ C2, float* __restrict__ QW) {
    __shared__ alignas(16) unsigned short Bs[9728];
    const int t = threadIdx.x, lane = t & 63;
    const int g = blockIdx.x * 4 + (t >> 6);
    const int col = lane & 15, slice = lane >> 4;
    const int row = g * 16 + col;

    short8b af[4];
    {
        const float* __restrict__ dr = dst_h + (size_t)row * 100;
        #pragma unroll
        for (int kc = 0; kc < 4; ++kc) {
            int k0 = kc * 32 + slice * 8;
            float4 xa = make_float4(0.f, 0.f, 0.f, 0.f), xb = xa;
            if (k0 + 8 <= 100) { xa = *(const float4*)(dr + k0); xb = *(const float4*)(dr + k0 + 4); }
            else if (k0 < 100)  { xa = *(const float4*)(dr + k0); }
            short8b a;
            a[0] = (short)f2bf(xa.x); a[1] = (short)f2bf(xa.y);
            a[2] = (short)f2bf(xa.z); a[3] = (short)f2bf(xa.w);
            a[4] = (short)f2bf(xb.x); a[5] = (short)f2bf(xb.y);
            a[6] = (short)f2bf(xb.z); a[7] = (short)f2bf(xb.w);
            af[kc] = a;
        }
    }
    const int re0 = g * 16 + (slice << 2);
    #pragma unroll
    for (int p = 0; p < 2; ++p) {
        f32x4 acc[19];
        #pragma unroll
        for (int nf = 0; nf < 19; ++nf) {
            int c = p * 304 + nf * 16 + col;
            float b = (c < 602) ? C2[c] : 0.f;
            acc[nf] = (f32x4){b, b, b, b};
        }
        #pragma unroll
        for (int kc = 0; kc < 4; ++kc) {
            {
                const float4* __restrict__ ws4 = (const float4*)Bq + (size_t)(p * 4 + kc) * 1216;
                float4* __restrict__ wd = (float4*)Bs;
                #pragma unroll
                for (int i = 0; i < 4; ++i) wd[i * 256 + t] = ws4[i * 256 + t];
                if (t < 192) wd[1024 + t] = ws4[1024 + t];
            }
            __syncthreads();
            #pragma unroll
            for (int nf = 0; nf < 19; ++nf) {
                short8b w = *(const short8b*)(&Bs[(size_t)(nf * 64 + lane) * 8]);
                acc[nf] = __builtin_amdgcn_mfma_f32_16x16x32_bf16(af[kc], w, acc[nf], 0, 0, 0);
            }
            __syncthreads();
        }
        #pragma unroll
        for (int nf = 0; nf < 19; ++nf) {
            int c = p * 304 + nf * 16 + col;
            if (c < 602) {
                #pragma unroll
                for (int r = 0; r < 4; ++r)
                    QW[(size_t)(re0 + r) * 608 + c] = acc[nf][r];
            }
        }
    }
}

// ---------- k_node: flash streaming, 1 wave/node (round-22 proven), 4-EDGE pipeline ----------
__global__ __launch_bounds__(256, 2) void k_node(
        const float* __restrict__ src_h, const float* __restrict__ efeat,
        const float* __restrict__ td,
        const float* __restrict__ time_w, const float* __restrict__ time_b,
        const float* __restrict__ QW, const int* __restrict__ off,
        float* __restrict__ Xagg) {
    const int lane = threadIdx.x & 63;
    const int n = blockIdx.x * 4 + (threadIdx.x >> 6);
    const int r0 = off[n], cnt = off[n + 1] - r0;
    float* __restrict__ xo = Xagg + (size_t)n * 600;
    if (cnt <= 0) {
        #pragma unroll
        for (int s = 0; s < 5; ++s) {
            int cc = s * 64 + lane;
            if (cc < 300) { xo[cc] = 0.f; xo[300 + cc] = 0.f; }
        }
        return;
    }
    float qw0[5], qw1[5];
    #pragma unroll
    for (int s = 0; s < 5; ++s) {
        int cc = s * 64 + lane;
        qw0[s] = (cc < 300) ? QW[(size_t)n * 608 + cc]       : 0.f;
        qw1[s] = (cc < 300) ? QW[(size_t)n * 608 + 300 + cc] : 0.f;
    }
    const float B0 = QW[(size_t)n * 608 + 600];
    const float B1 = QW[(size_t)n * 608 + 601];
    float tw3 = 0.f, tb3 = 0.f, tw4 = 0.f, tb4 = 0.f;
    if (lane >= 8) { tw3 = time_w[lane - 8]; tb3 = time_b[lane - 8]; }
    if (lane < 44) { tw4 = time_w[56 + lane]; tb4 = time_b[56 + lane]; }

    auto LOADX = [&](float* x, int r) {
        const float* __restrict__ sr = src_h + (size_t)r * 100;
        const float* __restrict__ er = efeat + (size_t)r * 100;
        const float tdv = td[r];
        x[0] = sr[lane];
        x[1] = (lane < 36) ? sr[64 + lane] : er[lane - 36];
        x[2] = er[28 + lane];
        x[3] = (lane < 8) ? er[92 + lane] : __cosf(fmaf(tdv, tw3, tb3));
        x[4] = (lane < 44) ? __cosf(fmaf(tdv, tw4, tb4)) : 0.f;
    };

    float m0 = -1e30f, m1 = -1e30f, sum0 = 0.f, sum1 = 0.f;
    float a0[5] = {0.f, 0.f, 0.f, 0.f, 0.f}, a1[5] = {0.f, 0.f, 0.f, 0.f, 0.f};

    auto UPDATE = [&](float l0, float l1, const float* x) {
        l0 = l0 > 0.f ? l0 : 0.2f * l0;
        l1 = l1 > 0.f ? l1 : 0.2f * l1;
        if (l0 <= m0 && l1 <= m1) {          // wave-uniform fast path (r == 1 exactly)
            float w0 = __expf(l0 - m0), w1 = __expf(l1 - m1);
            sum0 += w0; sum1 += w1;
            #pragma unroll
            for (int s = 0; s < 5; ++s) {
                a0[s] = fmaf(w0, x[s], a0[s]);
                a1[s] = fmaf(w1, x[s], a1[s]);
            }
        } else {
            float m0n = fmaxf(m0, l0), m1n = fmaxf(m1, l1);
            float r0f = __expf(m0 - m0n), r1f = __expf(m1 - m1n);
            float w0 = __expf(l0 - m0n),  w1 = __expf(l1 - m1n);
            sum0 = fmaf(sum0, r0f, w0);
            sum1 = fmaf(sum1, r1f, w1);
            #pragma unroll
            for (int s = 0; s < 5; ++s) {
                a0[s] = fmaf(a0[s], r0f, w0 * x[s]);
                a1[s] = fmaf(a1[s], r1f, w1 * x[s]);
            }
            m0 = m0n; m1 = m1n;
        }
    };

    auto TAIL1 = [&](const float* x) {       // dot + 2-chain butterfly + update
        float p0 = 0.f, p1 = 0.f;
        #pragma unroll
        for (int s = 0; s < 5; ++s) {
            p0 = fmaf(x[s], qw0[s], p0);
            p1 = fmaf(x[s], qw1[s], p1);
        }
        #pragma unroll
        for (int sh = 1; sh < 64; sh <<= 1) {
            p0 += __shfl_xor(p0, sh); p1 += __shfl_xor(p1, sh);
        }
        UPDATE(p0 + B0, p1 + B1, x);
    };

    float x0[5], x1[5], x2[5], x3[5];
    float y0[5], y1[5], y2[5], y3[5];
    int i = 0;
    if (cnt >= 4) {
        LOADX(x0, r0); LOADX(x1, r0 + 1); LOADX(x2, r0 + 2); LOADX(x3, r0 + 3);
        for (; i + 4 <= cnt; i += 4) {
            float p00 = 0.f, p01 = 0.f, p10 = 0.f, p11 = 0.f;
            float p20 = 0.f, p21 = 0.f, p30 = 0.f, p31 = 0.f;
            #pragma unroll
            for (int s = 0; s < 5; ++s) {
                p00 = fmaf(x0[s], qw0[s], p00); p01 = fmaf(x0[s], qw1[s], p01);
                p10 = fmaf(x1[s], qw0[s], p10); p11 = fmaf(x1[s], qw1[s], p11);
                p20 = fmaf(x2[s], qw0[s], p20); p21 = fmaf(x2[s], qw1[s], p21);
                p30 = fmaf(x3[s], qw0[s], p30); p31 = fmaf(x3[s], qw1[s], p31);
            }
            #pragma unroll
            for (int sh = 1; sh < 64; sh <<= 1) {   // 8 independent chains overlap
                p00 += __shfl_xor(p00, sh); p01 += __shfl_xor(p01, sh);
                p10 += __shfl_xor(p10, sh); p11 += __shfl_xor(p11, sh);
                p20 += __shfl_xor(p20, sh); p21 += __shfl_xor(p21, sh);
                p30 += __shfl_xor(p30, sh); p31 += __shfl_xor(p31, sh);
            }
            if (i + 4 < cnt) LOADX(y0, r0 + i + 4);  // prefetch next quad over updates
            if (i + 5 < cnt) LOADX(y1, r0 + i + 5);
            if (i + 6 < cnt) LOADX(y2, r0 + i + 6);
            if (i + 7 < cnt) LOADX(y3, r0 + i + 7);
            UPDATE(p00 + B0, p01 + B1, x0);
            UPDATE(p10 + B0, p11 + B1, x1);
            UPDATE(p20 + B0, p21 + B1, x2);
            UPDATE(p30 + B0, p31 + B1, x3);
            #pragma unroll
            for (int s = 0; s < 5; ++s) {
                x0[s] = y0[s]; x1[s] = y1[s]; x2[s] = y2[s]; x3[s] = y3[s];
            }
        }
    } else {
        if (cnt >= 1) LOADX(x0, r0);
        if (cnt >= 2) LOADX(x1, r0 + 1);
        if (cnt >= 3) LOADX(x2, r0 + 2);
    }
    const int rem = cnt - i;                 // 0..3; tail edges already in x0..x2
    if (rem > 0) TAIL1(x0);
    if (rem > 1) TAIL1(x1);
    if (rem > 2) TAIL1(x2);

    const float inv0 = 1.f / sum0, inv1 = 1.f / sum1;
    #pragma unroll
    for (int s = 0; s < 5; ++s) {
        int cc = s * 64 + lane;
        if (cc < 300) {
            xo[cc]       = a0[s] * inv0;
            xo[300 + cc] = a1[s] * inv1;
        }
    }
}

// ---------- k_aggv (MFMA): agg = Xagg @ Wbig + has*b_v ----------
__global__ __launch_bounds__(256, 1) void k_aggv(
        const float* __restrict__ Xagg, const unsigned short* __restrict__ Bv,
        const float* __restrict__ wkv_b, const int* __restrict__ off,
        float* __restrict__ agg) {
    __shared__ alignas(16) unsigned short Bs[10752];
    const int t = threadIdx.x, lane = t & 63;
    const int g = blockIdx.x * 4 + (t >> 6);
    const int col = lane & 15, slice = lane >> 4;
    const int row = g * 16 + col;

    short8b af[21];
    {
        const float* __restrict__ xr = Xagg + (size_t)row * 600;
        #pragma unroll
        for (int kc = 0; kc < 21; ++kc) {
            int j0 = kc * 32 + slice * 8;
            float4 xa = make_float4(0.f, 0.f, 0.f, 0.f), xb = xa;
            if (j0 + 8 <= 600) { xa = *(const float4*)(xr + j0); xb = *(const float4*)(xr + j0 + 4); }
            short8b a;
            a[0] = (short)f2bf(xa.x); a[1] = (short)f2bf(xa.y);
            a[2] = (short)f2bf(xa.z); a[3] = (short)f2bf(xa.w);
            a[4] = (short)f2bf(xb.x); a[5] = (short)f2bf(xb.y);
            a[6] = (short)f2bf(xb.z); a[7] = (short)f2bf(xb.w);
            af[kc] = a;
        }
    }
    f32x4 acc[7];
    #pragma unroll
    for (int nf = 0; nf < 7; ++nf) acc[nf] = (f32x4){0.f, 0.f, 0.f, 0.f};

    #pragma unroll
    for (int slab = 0; slab < 7; ++slab) {
        {
            const float4* __restrict__ ws4 = (const float4*)Bv + (size_t)slab * 1344;
            float4* __restrict__ wd = (float4*)Bs;
            #pragma unroll
            for (int i = 0; i < 5; ++i) wd[i * 256 + t] = ws4[i * 256 + t];
            if (t < 64) wd[1280 + t] = ws4[1280 + t];
        }
        __syncthreads();
        #pragma unroll
        for (int kl = 0; kl < 3; ++kl) {
            const int kc = slab * 3 + kl;
            #pragma unroll
            for (int nf = 0; nf < 7; ++nf) {
                short8b w = *(const short8b*)(&Bs[(size_t)((kl * 7 + nf) * 64 + lane) * 8]);
                acc[nf] = __builtin_amdgcn_mfma_f32_16x16x32_bf16(af[kc], w, acc[nf], 0, 0, 0);
            }
        }
        __syncthreads();
    }
    const int re0 = g * 16 + (slice << 2);
    #pragma unroll
    for (int nf = 0; nf < 7; ++nf) {
        int o = nf * 16 + col;
        if (o < 100) {
            float bv = wkv_b[100 + o];
            #pragma unroll
            for (int r = 0; r < 4; ++r) {
                int node = re0 + r;
                bool has = off[node + 1] > off[node];
                agg[(size_t)node * 100 + o] = acc[nf][r] + (has ? bv : 0.f);
            }
        }
    }
}

// ---------- out proj + relu + layernorm: 8 nodes/block, coalesced wout_t ----------
__global__ __launch_bounds__(128) void k_out(const float* __restrict__ agg,
                                             const float* __restrict__ dst_h,
                                             const float* __restrict__ wout_t,
                                             const float* __restrict__ wout_b,
                                             const float* __restrict__ ln_g,
                                             const float* __restrict__ ln_b,
                                             float* __restrict__ out) {
    __shared__ float Fs[8][200];
    __shared__ float red[8][128];
    const int n0 = blockIdx.x * 8, t = threadIdx.x;
    for (int idx = t; idx < 1600; idx += 128) {
        int n = idx / 200, i = idx % 200;
        Fs[n][i] = (i < 100) ? agg[(size_t)(n0 + n) * 100 + i]
                             : dst_h[(size_t)(n0 + n) * 100 + (i - 100)];
    }
    __syncthreads();
    float v[8] = {0.f, 0.f, 0.f, 0.f, 0.f, 0.f, 0.f, 0.f};
    if (t < 100) {
        float b = wout_b[t];
        #pragma unroll
        for (int n = 0; n < 8; ++n) v[n] = b;
        for (int i = 0; i < 200; ++i) {
            float w = wout_t[i * 100 + t];
            #pragma unroll
            for (int n = 0; n < 8; ++n) v[n] = fmaf(Fs[n][i], w, v[n]);
        }
        #pragma unroll
        for (int n = 0; n < 8; ++n) v[n] = fmaxf(v[n], 0.f);
    }
    #pragma unroll
    for (int n = 0; n < 8; ++n) red[n][t] = (t < 100) ? v[n] : 0.f;
    __syncthreads();
    for (int s = 64; s > 0; s >>= 1) {
        if (t < s) {
            #pragma unroll
            for (int n = 0; n < 8; ++n) red[n][t] += red[n][t + s];
        }
        __syncthreads();
    }
    float mu[8];
    #pragma unroll
    for (int n = 0; n < 8; ++n) mu[n] = red[n][0] * 0.01f;
    __syncthreads();
    #pragma unroll
    for (int n = 0; n < 8; ++n) {
        float dv = (t < 100) ? (v[n] - mu[n]) : 0.f;
        red[n][t] = dv * dv;
    }
    __syncthreads();
    for (int s = 64; s > 0; s >>= 1) {
        if (t < s) {
            #pragma unroll
            for (int n = 0; n < 8; ++n) red[n][t] += red[n][t + s];
        }
        __syncthreads();
    }
    if (t < 100) {
        #pragma unroll
        for (int n = 0; n < 8; ++n) {
            float var = red[n][0] * 0.01f;
            out[(size_t)(n0 + n) * 100 + t] =
                (v[n] - mu[n]) * rsqrtf(var + LN_EPS) * ln_g[t] + ln_b[t];
        }
    }
}

extern "C" void kernel_launch(void* const* d_in, const int* in_sizes, int n_in,
                              void* d_out, int out_size, void* d_ws, size_t ws_size,
                              hipStream_t stream) {
    const float* dst_h   = (const float*)d_in[0];
    const float* src_h   = (const float*)d_in[1];
    const float* efeat   = (const float*)d_in[2];
    const float* td      = (const float*)d_in[3];
    const int*   edst    = (const int*)  d_in[4];
    const float* time_w  = (const float*)d_in[5];
    const float* time_b  = (const float*)d_in[6];
    const float* wq_w    = (const float*)d_in[7];
    const float* wq_b    = (const float*)d_in[8];
    const float* wkv_w   = (const float*)d_in[9];
    const float* wkv_b   = (const float*)d_in[10];
    const float* wout_w  = (const float*)d_in[11];
    const float* wout_b  = (const float*)d_in[12];
    const float* ln_g    = (const float*)d_in[13];
    const float* ln_b    = (const float*)d_in[14];
    float* out = (float*)d_out;

    char* ws = (char*)d_ws;
    size_t off = 0;
    auto carve = [&](size_t bytes) { char* p = ws + off; off = (off + bytes + 255) & ~(size_t)255; return p; };
    float*          QW    = (float*)carve((size_t)N_DST * 608 * 4);
    float*          Xagg  = (float*)carve((size_t)N_DST * 600 * 4);
    float*          agg   = (float*)carve((size_t)N_DST * 100 * 4);
    float*          A2    = (float*)carve(60200 * 4);
    float*          C2    = (float*)carve(602 * 4);
    unsigned short* Bq    = (unsigned short*)carve(77824 * 2);
    unsigned short* Bv    = (unsigned short*)carve(75264 * 2);
    float*          woutT = (float*)carve(20000 * 4);
    float*          zq    = (float*)carve(100 * 4);
    int*            offs  = (int*)carve((size_t)(N_DST + 1) * 4);

    k_prep<<<(95364 + 255) / 256, 256, 0, stream>>>(wkv_w, wq_w, wq_b, time_b, wout_w,
                                                    zq, woutT, Bv);
    k_precomp<<<(60802 + 255) / 256, 256, 0, stream>>>(wq_w, wkv_w, wkv_b, zq, A2, C2);
    k_pack<<<(77824 + 255) / 256, 256, 0, stream>>>(A2, Bq);
    k_offsets<<<(N_DST + 1 + 255) / 256, 256, 0, stream>>>(edst, offs);
    k_qw<<<N_DST / 64, 256, 0, stream>>>(dst_h, Bq, C2, QW);
    k_node<<<N_DST / 4, 256, 0, stream>>>(src_h, efeat, td, time_w, time_b,
                                          QW, offs, Xagg);
    k_aggv<<<N_DST / 64, 256, 0, stream>>>(Xagg, Bv, wkv_b, offs, agg);
    k_out<<<N_DST / 8, 128, 0, stream>>>(agg, dst_h, woutT, wout_b, ln_g, ln_b, out);
}

// Round 25
// 324.119 us; speedup vs baseline: 1.0511x; 1.0511x over previous
//
#include <hip/hip_runtime.h>
#include <math.h>

#define N_DST   32768
#define N_EDGE  524288
#define LN_EPS  1e-5f

typedef __attribute__((ext_vector_type(8))) short short8b;   // 8 bf16 (4 VGPR)
typedef __attribute__((ext_vector_type(4))) float f32x4;

static __device__ __forceinline__ unsigned short f2bf(float f) {
    unsigned u = __float_as_uint(f);
    u += 0x7fff + ((u >> 16) & 1);          // round-to-nearest-even
    return (unsigned short)(u >> 16);
}

// ---------- prep: zq, wout^T, Bv pack (block-diag V weights -> MFMA B-frag order) ----------
__global__ void k_prep(const float* __restrict__ wkv_w, const float* __restrict__ wq_w,
                       const float* __restrict__ wq_b, const float* __restrict__ time_b,
                       const float* __restrict__ wout_w,
                       float* __restrict__ zq, float* __restrict__ wout_t,
                       unsigned short* __restrict__ Bv) {
    int idx = blockIdx.x * 256 + threadIdx.x;
    if (idx < 100) {
        float acc = wq_b[idx];
        for (int j = 0; j < 100; ++j)
            acc += cosf(time_b[j]) * wq_w[idx * 200 + 100 + j];
        zq[idx] = acc;
    } else if (idx < 20100) {
        int r = idx - 100;                      // wout_t[i][o] = wout_w[o][i]
        wout_t[r] = wout_w[(size_t)(r % 100) * 200 + r / 100];
    } else if (idx < 95364) {
        int r2 = idx - 20100;
        int jj = r2 & 7, l = (r2 >> 3) & 63, nf = (r2 >> 9) % 7, kc = r2 / 3584;
        int j = kc * 32 + ((l >> 4) << 3) + jj;
        int o = nf * 16 + (l & 15);
        float v = (j < 600 && o < 100 && (j / 300 == o / 50))
                  ? wkv_w[(size_t)(100 + o) * 300 + (j % 300)] : 0.f;
        Bv[r2] = f2bf(v);
    }
}

// ---------- k_precomp: QW-map computed DIRECTLY in MFMA B-frag packed order ----------
// Bq[p<2][kc<4][nf<19][l][jj] = A2[k][c] (bf16), k=kc*32+((l>>4)<<3)+jj, c=p*304+nf*16+(l&15)
// A2[i][j<600] = sum_d wq_w[h*50+d][i]*wkv_w[h*50+d][j%300]; j=600+h: K-bias dot.
// C2[j] = same contraction with zq. (A2 never materialized; k_pack eliminated.)
__global__ void k_precomp(const float* __restrict__ wq_w, const float* __restrict__ wkv_w,
                          const float* __restrict__ wkv_b, const float* __restrict__ zq,
                          unsigned short* __restrict__ Bq, float* __restrict__ C2) {
    int idx = blockIdx.x * 256 + threadIdx.x;
    if (idx < 77824) {
        int jj = idx & 7, l = (idx >> 3) & 63, nf = (idx >> 9) % 19, kcp = idx / 9728;
        int kc = kcp & 3, p = kcp >> 2;
        int i = kc * 32 + ((l >> 4) << 3) + jj;          // row of A2 (dst_h dim)
        int j = p * 304 + nf * 16 + (l & 15);            // col of A2
        float acc = 0.f;
        if (i < 100 && j < 602) {
            if (j < 600) {
                int h = j / 300, cc = j % 300;
                const float* __restrict__ wq = wq_w + (size_t)(h * 50) * 200 + i;
                const float* __restrict__ wk = wkv_w + (size_t)(h * 50) * 300 + cc;
                #pragma unroll 10
                for (int d = 0; d < 50; ++d)
                    acc = fmaf(wq[(size_t)d * 200], wk[(size_t)d * 300], acc);
            } else {
                int h = j - 600;
                const float* __restrict__ wq = wq_w + (size_t)(h * 50) * 200 + i;
                for (int d = 0; d < 50; ++d)
                    acc = fmaf(wq[(size_t)d * 200], wkv_b[h * 50 + d], acc);
            }
        }
        Bq[idx] = f2bf(acc);
    } else if (idx < 78426) {
        int j = idx - 77824;
        float acc = 0.f;
        if (j < 600) {
            int h = j / 300, cc = j % 300;
            for (int d = 0; d < 50; ++d)
                acc = fmaf(zq[h * 50 + d], wkv_w[(size_t)(h * 50 + d) * 300 + cc], acc);
        } else {
            int h = j - 600;
            for (int d = 0; d < 50; ++d)
                acc = fmaf(zq[h * 50 + d], wkv_b[h * 50 + d], acc);
        }
        C2[j] = acc;
    }
}

// ---------- CSR offsets via binary search over sorted edge_dst ----------
__global__ void k_offsets(const int* __restrict__ dst, int* __restrict__ off) {
    int n = blockIdx.x * 256 + threadIdx.x;
    if (n > N_DST) return;
    int lo = 0, hi = N_EDGE;
    while (lo < hi) {
        int mid = (lo + hi) >> 1;
        if (dst[mid] < n) lo = mid + 1; else hi = mid;
    }
    off[n] = lo;
}

// ---------- k_qw (MFMA): QW[32768x602] = dst_h @ A2 + C2 ----------
__global__ __launch_bounds__(256, 1) void k_qw(
        const float* __restrict__ dst_h, const unsigned short* __restrict__ Bq,
        const float* __restrict__ C2, float* __restrict__ QW) {
    __shared__ alignas(16) unsigned short Bs[9728];
    const int t = threadIdx.x, lane = t & 63;
    const int g = blockIdx.x * 4 + (t >> 6);
    const int col = lane & 15, slice = lane >> 4;
    const int row = g * 16 + col;

    short8b af[4];
    {
        const float* __restrict__ dr = dst_h + (size_t)row * 100;
        #pragma unroll
        for (int kc = 0; kc < 4; ++kc) {
            int k0 = kc * 32 + slice * 8;
            float4 xa = make_float4(0.f, 0.f, 0.f, 0.f), xb = xa;
            if (k0 + 8 <= 100) { xa = *(const float4*)(dr + k0); xb = *(const float4*)(dr + k0 + 4); }
            else if (k0 < 100)  { xa = *(const float4*)(dr + k0); }
            short8b a;
            a[0] = (short)f2bf(xa.x); a[1] = (short)f2bf(xa.y);
            a[2] = (short)f2bf(xa.z); a[3] = (short)f2bf(xa.w);
            a[4] = (short)f2bf(xb.x); a[5] = (short)f2bf(xb.y);
            a[6] = (short)f2bf(xb.z); a[7] = (short)f2bf(xb.w);
            af[kc] = a;
        }
    }
    const int re0 = g * 16 + (slice << 2);
    #pragma unroll
    for (int p = 0; p < 2; ++p) {
        f32x4 acc[19];
        #pragma unroll
        for (int nf = 0; nf < 19; ++nf) {
            int c = p * 304 + nf * 16 + col;
            float b = (c < 602) ? C2[c] : 0.f;
            acc[nf] = (f32x4){b, b, b, b};
        }
        #pragma unroll
        for (int kc = 0; kc < 4; ++kc) {
            {
                const float4* __restrict__ ws4 = (const float4*)Bq + (size_t)(p * 4 + kc) * 1216;
                float4* __restrict__ wd = (float4*)Bs;
                #pragma unroll
                for (int i = 0; i < 4; ++i) wd[i * 256 + t] = ws4[i * 256 + t];
                if (t < 192) wd[1024 + t] = ws4[1024 + t];
            }
            __syncthreads();
            #pragma unroll
            for (int nf = 0; nf < 19; ++nf) {
                short8b w = *(const short8b*)(&Bs[(size_t)(nf * 64 + lane) * 8]);
                acc[nf] = __builtin_amdgcn_mfma_f32_16x16x32_bf16(af[kc], w, acc[nf], 0, 0, 0);
            }
            __syncthreads();
        }
        #pragma unroll
        for (int nf = 0; nf < 19; ++nf) {
            int c = p * 304 + nf * 16 + col;
            if (c < 602) {
                #pragma unroll
                for (int r = 0; r < 4; ++r)
                    QW[(size_t)(re0 + r) * 608 + c] = acc[nf][r];
            }
        }
    }
}

// ---------- k_node: flash streaming, 1 wave/node, 2-edge pipeline (round-22 proven) ----------
__global__ __launch_bounds__(256) void k_node(
        const float* __restrict__ src_h, const float* __restrict__ efeat,
        const float* __restrict__ td,
        const float* __restrict__ time_w, const float* __restrict__ time_b,
        const float* __restrict__ QW, const int* __restrict__ off,
        float* __restrict__ Xagg) {
    const int lane = threadIdx.x & 63;
    const int n = blockIdx.x * 4 + (threadIdx.x >> 6);
    const int r0 = off[n], cnt = off[n + 1] - r0;
    float* __restrict__ xo = Xagg + (size_t)n * 600;
    if (cnt <= 0) {
        #pragma unroll
        for (int s = 0; s < 5; ++s) {
            int cc = s * 64 + lane;
            if (cc < 300) { xo[cc] = 0.f; xo[300 + cc] = 0.f; }
        }
        return;
    }
    float qw0[5], qw1[5];
    #pragma unroll
    for (int s = 0; s < 5; ++s) {
        int cc = s * 64 + lane;
        qw0[s] = (cc < 300) ? QW[(size_t)n * 608 + cc]       : 0.f;
        qw1[s] = (cc < 300) ? QW[(size_t)n * 608 + 300 + cc] : 0.f;
    }
    const float B0 = QW[(size_t)n * 608 + 600];
    const float B1 = QW[(size_t)n * 608 + 601];
    float tw3 = 0.f, tb3 = 0.f, tw4 = 0.f, tb4 = 0.f;
    if (lane >= 8) { tw3 = time_w[lane - 8]; tb3 = time_b[lane - 8]; }
    if (lane < 44) { tw4 = time_w[56 + lane]; tb4 = time_b[56 + lane]; }

    auto LOADX = [&](float* x, int r) {
        const float* __restrict__ sr = src_h + (size_t)r * 100;
        const float* __restrict__ er = efeat + (size_t)r * 100;
        const float tdv = td[r];
        x[0] = sr[lane];
        x[1] = (lane < 36) ? sr[64 + lane] : er[lane - 36];
        x[2] = er[28 + lane];
        x[3] = (lane < 8) ? er[92 + lane] : __cosf(fmaf(tdv, tw3, tb3));
        x[4] = (lane < 44) ? __cosf(fmaf(tdv, tw4, tb4)) : 0.f;
    };

    float m0 = -1e30f, m1 = -1e30f, sum0 = 0.f, sum1 = 0.f;
    float a0[5] = {0.f, 0.f, 0.f, 0.f, 0.f}, a1[5] = {0.f, 0.f, 0.f, 0.f, 0.f};

    auto UPDATE = [&](float l0, float l1, const float* x) {
        l0 = l0 > 0.f ? l0 : 0.2f * l0;
        l1 = l1 > 0.f ? l1 : 0.2f * l1;
        if (l0 <= m0 && l1 <= m1) {          // wave-uniform fast path (r == 1 exactly)
            float w0 = __expf(l0 - m0), w1 = __expf(l1 - m1);
            sum0 += w0; sum1 += w1;
            #pragma unroll
            for (int s = 0; s < 5; ++s) {
                a0[s] = fmaf(w0, x[s], a0[s]);
                a1[s] = fmaf(w1, x[s], a1[s]);
            }
        } else {
            float m0n = fmaxf(m0, l0), m1n = fmaxf(m1, l1);
            float r0f = __expf(m0 - m0n), r1f = __expf(m1 - m1n);
            float w0 = __expf(l0 - m0n),  w1 = __expf(l1 - m1n);
            sum0 = fmaf(sum0, r0f, w0);
            sum1 = fmaf(sum1, r1f, w1);
            #pragma unroll
            for (int s = 0; s < 5; ++s) {
                a0[s] = fmaf(a0[s], r0f, w0 * x[s]);
                a1[s] = fmaf(a1[s], r1f, w1 * x[s]);
            }
            m0 = m0n; m1 = m1n;
        }
    };

    float xA[5], xB[5], xC[5], xD[5];
    int i = 0;
    if (cnt >= 2) {
        LOADX(xA, r0); LOADX(xB, r0 + 1);
        for (; i + 2 <= cnt; i += 2) {
            float pA0 = 0.f, pA1 = 0.f, pB0 = 0.f, pB1 = 0.f;
            #pragma unroll
            for (int s = 0; s < 5; ++s) {
                pA0 = fmaf(xA[s], qw0[s], pA0); pA1 = fmaf(xA[s], qw1[s], pA1);
                pB0 = fmaf(xB[s], qw0[s], pB0); pB1 = fmaf(xB[s], qw1[s], pB1);
            }
            #pragma unroll
            for (int sh = 1; sh < 64; sh <<= 1) {
                pA0 += __shfl_xor(pA0, sh); pA1 += __shfl_xor(pA1, sh);
                pB0 += __shfl_xor(pB0, sh); pB1 += __shfl_xor(pB1, sh);
            }
            if (i + 2 < cnt) LOADX(xC, r0 + i + 2);
            if (i + 3 < cnt) LOADX(xD, r0 + i + 3);
            UPDATE(pA0 + B0, pA1 + B1, xA);
            UPDATE(pB0 + B0, pB1 + B1, xB);
            #pragma unroll
            for (int s = 0; s < 5; ++s) { xA[s] = xC[s]; xB[s] = xD[s]; }
        }
    } else {
        LOADX(xA, r0);
    }
    if (i < cnt) {
        float p0 = 0.f, p1 = 0.f;
        #pragma unroll
        for (int s = 0; s < 5; ++s) {
            p0 = fmaf(xA[s], qw0[s], p0);
            p1 = fmaf(xA[s], qw1[s], p1);
        }
        #pragma unroll
        for (int sh = 1; sh < 64; sh <<= 1) {
            p0 += __shfl_xor(p0, sh); p1 += __shfl_xor(p1, sh);
        }
        UPDATE(p0 + B0, p1 + B1, xA);
    }
    const float inv0 = 1.f / sum0, inv1 = 1.f / sum1;
    #pragma unroll
    for (int s = 0; s < 5; ++s) {
        int cc = s * 64 + lane;
        if (cc < 300) {
            xo[cc]       = a0[s] * inv0;
            xo[300 + cc] = a1[s] * inv1;
        }
    }
}

// ---------- k_aggv (MFMA): agg = Xagg @ Wbig + has*b_v ----------
__global__ __launch_bounds__(256, 1) void k_aggv(
        const float* __restrict__ Xagg, const unsigned short* __restrict__ Bv,
        const float* __restrict__ wkv_b, const int* __restrict__ off,
        float* __restrict__ agg) {
    __shared__ alignas(16) unsigned short Bs[10752];
    const int t = threadIdx.x, lane = t & 63;
    const int g = blockIdx.x * 4 + (t >> 6);
    const int col = lane & 15, slice = lane >> 4;
    const int row = g * 16 + col;

    short8b af[21];
    {
        const float* __restrict__ xr = Xagg + (size_t)row * 600;
        #pragma unroll
        for (int kc = 0; kc < 21; ++kc) {
            int j0 = kc * 32 + slice * 8;
            float4 xa = make_float4(0.f, 0.f, 0.f, 0.f), xb = xa;
            if (j0 + 8 <= 600) { xa = *(const float4*)(xr + j0); xb = *(const float4*)(xr + j0 + 4); }
            short8b a;
            a[0] = (short)f2bf(xa.x); a[1] = (short)f2bf(xa.y);
            a[2] = (short)f2bf(xa.z); a[3] = (short)f2bf(xa.w);
            a[4] = (short)f2bf(xb.x); a[5] = (short)f2bf(xb.y);
            a[6] = (short)f2bf(xb.z); a[7] = (short)f2bf(xb.w);
            af[kc] = a;
        }
    }
    f32x4 acc[7];
    #pragma unroll
    for (int nf = 0; nf < 7; ++nf) acc[nf] = (f32x4){0.f, 0.f, 0.f, 0.f};

    #pragma unroll
    for (int slab = 0; slab < 7; ++slab) {
        {
            const float4* __restrict__ ws4 = (const float4*)Bv + (size_t)slab * 1344;
            float4* __restrict__ wd = (float4*)Bs;
            #pragma unroll
            for (int i = 0; i < 5; ++i) wd[i * 256 + t] = ws4[i * 256 + t];
            if (t < 64) wd[1280 + t] = ws4[1280 + t];
        }
        __syncthreads();
        #pragma unroll
        for (int kl = 0; kl < 3; ++kl) {
            const int kc = slab * 3 + kl;
            #pragma unroll
            for (int nf = 0; nf < 7; ++nf) {
                short8b w = *(const short8b*)(&Bs[(size_t)((kl * 7 + nf) * 64 + lane) * 8]);
                acc[nf] = __builtin_amdgcn_mfma_f32_16x16x32_bf16(af[kc], w, acc[nf], 0, 0, 0);
            }
        }
        __syncthreads();
    }
    const int re0 = g * 16 + (slice << 2);
    #pragma unroll
    for (int nf = 0; nf < 7; ++nf) {
        int o = nf * 16 + col;
        if (o < 100) {
            float bv = wkv_b[100 + o];
            #pragma unroll
            for (int r = 0; r < 4; ++r) {
                int node = re0 + r;
                bool has = off[node + 1] > off[node];
                agg[(size_t)node * 100 + o] = acc[nf][r] + (has ? bv : 0.f);
            }
        }
    }
}

// ---------- out proj + relu + layernorm: 8 nodes/block, coalesced wout_t ----------
__global__ __launch_bounds__(128) void k_out(const float* __restrict__ agg,
                                             const float* __restrict__ dst_h,
                                             const float* __restrict__ wout_t,
                                             const float* __restrict__ wout_b,
                                             const float* __restrict__ ln_g,
                                             const float* __restrict__ ln_b,
                                             float* __restrict__ out) {
    __shared__ float Fs[8][200];
    __shared__ float red[8][128];
    const int n0 = blockIdx.x * 8, t = threadIdx.x;
    for (int idx = t; idx < 1600; idx += 128) {
        int n = idx / 200, i = idx % 200;
        Fs[n][i] = (i < 100) ? agg[(size_t)(n0 + n) * 100 + i]
                             : dst_h[(size_t)(n0 + n) * 100 + (i - 100)];
    }
    __syncthreads();
    float v[8] = {0.f, 0.f, 0.f, 0.f, 0.f, 0.f, 0.f, 0.f};
    if (t < 100) {
        float b = wout_b[t];
        #pragma unroll
        for (int n = 0; n < 8; ++n) v[n] = b;
        for (int i = 0; i < 200; ++i) {
            float w = wout_t[i * 100 + t];
            #pragma unroll
            for (int n = 0; n < 8; ++n) v[n] = fmaf(Fs[n][i], w, v[n]);
        }
        #pragma unroll
        for (int n = 0; n < 8; ++n) v[n] = fmaxf(v[n], 0.f);
    }
    #pragma unroll
    for (int n = 0; n < 8; ++n) red[n][t] = (t < 100) ? v[n] : 0.f;
    __syncthreads();
    for (int s = 64; s > 0; s >>= 1) {
        if (t < s) {
            #pragma unroll
            for (int n = 0; n < 8; ++n) red[n][t] += red[n][t + s];
        }
        __syncthreads();
    }
    float mu[8];
    #pragma unroll
    for (int n = 0; n < 8; ++n) mu[n] = red[n][0] * 0.01f;
    __syncthreads();
    #pragma unroll
    for (int n = 0; n < 8; ++n) {
        float dv = (t < 100) ? (v[n] - mu[n]) : 0.f;
        red[n][t] = dv * dv;
    }
    __syncthreads();
    for (int s = 64; s > 0; s >>= 1) {
        if (t < s) {
            #pragma unroll
            for (int n = 0; n < 8; ++n) red[n][t] += red[n][t + s];
        }
        __syncthreads();
    }
    if (t < 100) {
        #pragma unroll
        for (int n = 0; n < 8; ++n) {
            float var = red[n][0] * 0.01f;
            out[(size_t)(n0 + n) * 100 + t] =
                (v[n] - mu[n]) * rsqrtf(var + LN_EPS) * ln_g[t] + ln_b[t];
        }
    }
}

extern "C" void kernel_launch(void* const* d_in, const int* in_sizes, int n_in,
                              void* d_out, int out_size, void* d_ws, size_t ws_size,
                              hipStream_t stream) {
    const float* dst_h   = (const float*)d_in[0];
    const float* src_h   = (const float*)d_in[1];
    const float* efeat   = (const float*)d_in[2];
    const float* td      = (const float*)d_in[3];
    const int*   edst    = (const int*)  d_in[4];
    const float* time_w  = (const float*)d_in[5];
    const float* time_b  = (const float*)d_in[6];
    const float* wq_w    = (const float*)d_in[7];
    const float* wq_b    = (const float*)d_in[8];
    const float* wkv_w   = (const float*)d_in[9];
    const float* wkv_b   = (const float*)d_in[10];
    const float* wout_w  = (const float*)d_in[11];
    const float* wout_b  = (const float*)d_in[12];
    const float* ln_g    = (const float*)d_in[13];
    const float* ln_b    = (const float*)d_in[14];
    float* out = (float*)d_out;

    char* ws = (char*)d_ws;
    size_t off = 0;
    auto carve = [&](size_t bytes) { char* p = ws + off; off = (off + bytes + 255) & ~(size_t)255; return p; };
    float*          QW    = (float*)carve((size_t)N_DST * 608 * 4);
    float*          Xagg  = (float*)carve((size_t)N_DST * 600 * 4);
    float*          agg   = (float*)carve((size_t)N_DST * 100 * 4);
    float*          C2    = (float*)carve(602 * 4);
    unsigned short* Bq    = (unsigned short*)carve(77824 * 2);
    unsigned short* Bv    = (unsigned short*)carve(75264 * 2);
    float*          woutT = (float*)carve(20000 * 4);
    float*          zq    = (float*)carve(100 * 4);
    int*            offs  = (int*)carve((size_t)(N_DST + 1) * 4);

    k_prep<<<(95364 + 255) / 256, 256, 0, stream>>>(wkv_w, wq_w, wq_b, time_b, wout_w,
                                                    zq, woutT, Bv);
    k_precomp<<<(78426 + 255) / 256, 256, 0, stream>>>(wq_w, wkv_w, wkv_b, zq, Bq, C2);
    k_offsets<<<(N_DST + 1 + 255) / 256, 256, 0, stream>>>(edst, offs);
    k_qw<<<N_DST / 64, 256, 0, stream>>>(dst_h, Bq, C2, QW);
    k_node<<<N_DST / 4, 256, 0, stream>>>(src_h, efeat, td, time_w, time_b,
                                          QW, offs, Xagg);
    k_aggv<<<N_DST / 64, 256, 0, stream>>>(Xagg, Bv, wkv_b, offs, agg);
    k_out<<<N_DST / 8, 128, 0, stream>>>(agg, dst_h, woutT, wout_b, ln_g, ln_b, out);
}

// Round 26
// 314.073 us; speedup vs baseline: 1.0847x; 1.0320x over previous
//
#include <hip/hip_runtime.h>
#include <math.h>

#define N_DST   32768
#define N_EDGE  524288
#define LN_EPS  1e-5f

typedef __attribute__((ext_vector_type(8))) short short8b;   // 8 bf16 (4 VGPR)
typedef __attribute__((ext_vector_type(4))) float f32x4;

static __device__ __forceinline__ unsigned short f2bf(float f) {
    unsigned u = __float_as_uint(f);
    u += 0x7fff + ((u >> 16) & 1);          // round-to-nearest-even
    return (unsigned short)(u >> 16);
}
static __device__ __forceinline__ float bf2f(unsigned short s) {
    return __uint_as_float(((unsigned)s) << 16);
}

// ---------- prep: zq, wout^T, Bv pack (block-diag V weights -> MFMA B-frag order) ----------
__global__ void k_prep(const float* __restrict__ wkv_w, const float* __restrict__ wq_w,
                       const float* __restrict__ wq_b, const float* __restrict__ time_b,
                       const float* __restrict__ wout_w,
                       float* __restrict__ zq, float* __restrict__ wout_t,
                       unsigned short* __restrict__ Bv) {
    int idx = blockIdx.x * 256 + threadIdx.x;
    if (idx < 100) {
        float acc = wq_b[idx];
        for (int j = 0; j < 100; ++j)
            acc += cosf(time_b[j]) * wq_w[idx * 200 + 100 + j];
        zq[idx] = acc;
    } else if (idx < 20100) {
        int r = idx - 100;                      // wout_t[i][o] = wout_w[o][i]
        wout_t[r] = wout_w[(size_t)(r % 100) * 200 + r / 100];
    } else if (idx < 95364) {
        int r2 = idx - 20100;
        int jj = r2 & 7, l = (r2 >> 3) & 63, nf = (r2 >> 9) % 7, kc = r2 / 3584;
        int j = kc * 32 + ((l >> 4) << 3) + jj;
        int o = nf * 16 + (l & 15);
        float v = (j < 600 && o < 100 && (j / 300 == o / 50))
                  ? wkv_w[(size_t)(100 + o) * 300 + (j % 300)] : 0.f;
        Bv[r2] = f2bf(v);
    }
}

// ---------- k_precomp: QW-map computed DIRECTLY in MFMA B-frag packed order ----------
__global__ void k_precomp(const float* __restrict__ wq_w, const float* __restrict__ wkv_w,
                          const float* __restrict__ wkv_b, const float* __restrict__ zq,
                          unsigned short* __restrict__ Bq, float* __restrict__ C2) {
    int idx = blockIdx.x * 256 + threadIdx.x;
    if (idx < 77824) {
        int jj = idx & 7, l = (idx >> 3) & 63, nf = (idx >> 9) % 19, kcp = idx / 9728;
        int kc = kcp & 3, p = kcp >> 2;
        int i = kc * 32 + ((l >> 4) << 3) + jj;
        int j = p * 304 + nf * 16 + (l & 15);
        float acc = 0.f;
        if (i < 100 && j < 602) {
            if (j < 600) {
                int h = j / 300, cc = j % 300;
                const float* __restrict__ wq = wq_w + (size_t)(h * 50) * 200 + i;
                const float* __restrict__ wk = wkv_w + (size_t)(h * 50) * 300 + cc;
                #pragma unroll 10
                for (int d = 0; d < 50; ++d)
                    acc = fmaf(wq[(size_t)d * 200], wk[(size_t)d * 300], acc);
            } else {
                int h = j - 600;
                const float* __restrict__ wq = wq_w + (size_t)(h * 50) * 200 + i;
                for (int d = 0; d < 50; ++d)
                    acc = fmaf(wq[(size_t)d * 200], wkv_b[h * 50 + d], acc);
            }
        }
        Bq[idx] = f2bf(acc);
    } else if (idx < 78426) {
        int j = idx - 77824;
        float acc = 0.f;
        if (j < 600) {
            int h = j / 300, cc = j % 300;
            for (int d = 0; d < 50; ++d)
                acc = fmaf(zq[h * 50 + d], wkv_w[(size_t)(h * 50 + d) * 300 + cc], acc);
        } else {
            int h = j - 600;
            for (int d = 0; d < 50; ++d)
                acc = fmaf(zq[h * 50 + d], wkv_b[h * 50 + d], acc);
        }
        C2[j] = acc;
    }
}

// ---------- CSR offsets via binary search over sorted edge_dst ----------
__global__ void k_offsets(const int* __restrict__ dst, int* __restrict__ off) {
    int n = blockIdx.x * 256 + threadIdx.x;
    if (n > N_DST) return;
    int lo = 0, hi = N_EDGE;
    while (lo < hi) {
        int mid = (lo + hi) >> 1;
        if (dst[mid] < n) lo = mid + 1; else hi = mid;
    }
    off[n] = lo;
}

// ---------- k_qw (MFMA): QW[32768x602] = dst_h @ A2 + C2, stored as BF16 ----------
__global__ __launch_bounds__(256, 1) void k_qw(
        const float* __restrict__ dst_h, const unsigned short* __restrict__ Bq,
        const float* __restrict__ C2, unsigned short* __restrict__ QW) {
    __shared__ alignas(16) unsigned short Bs[9728];
    const int t = threadIdx.x, lane = t & 63;
    const int g = blockIdx.x * 4 + (t >> 6);
    const int col = lane & 15, slice = lane >> 4;
    const int row = g * 16 + col;

    short8b af[4];
    {
        const float* __restrict__ dr = dst_h + (size_t)row * 100;
        #pragma unroll
        for (int kc = 0; kc < 4; ++kc) {
            int k0 = kc * 32 + slice * 8;
            float4 xa = make_float4(0.f, 0.f, 0.f, 0.f), xb = xa;
            if (k0 + 8 <= 100) { xa = *(const float4*)(dr + k0); xb = *(const float4*)(dr + k0 + 4); }
            else if (k0 < 100)  { xa = *(const float4*)(dr + k0); }
            short8b a;
            a[0] = (short)f2bf(xa.x); a[1] = (short)f2bf(xa.y);
            a[2] = (short)f2bf(xa.z); a[3] = (short)f2bf(xa.w);
            a[4] = (short)f2bf(xb.x); a[5] = (short)f2bf(xb.y);
            a[6] = (short)f2bf(xb.z); a[7] = (short)f2bf(xb.w);
            af[kc] = a;
        }
    }
    const int re0 = g * 16 + (slice << 2);
    #pragma unroll
    for (int p = 0; p < 2; ++p) {
        f32x4 acc[19];
        #pragma unroll
        for (int nf = 0; nf < 19; ++nf) {
            int c = p * 304 + nf * 16 + col;
            float b = (c < 602) ? C2[c] : 0.f;
            acc[nf] = (f32x4){b, b, b, b};
        }
        #pragma unroll
        for (int kc = 0; kc < 4; ++kc) {
            {
                const float4* __restrict__ ws4 = (const float4*)Bq + (size_t)(p * 4 + kc) * 1216;
                float4* __restrict__ wd = (float4*)Bs;
                #pragma unroll
                for (int i = 0; i < 4; ++i) wd[i * 256 + t] = ws4[i * 256 + t];
                if (t < 192) wd[1024 + t] = ws4[1024 + t];
            }
            __syncthreads();
            #pragma unroll
            for (int nf = 0; nf < 19; ++nf) {
                short8b w = *(const short8b*)(&Bs[(size_t)(nf * 64 + lane) * 8]);
                acc[nf] = __builtin_amdgcn_mfma_f32_16x16x32_bf16(af[kc], w, acc[nf], 0, 0, 0);
            }
            __syncthreads();
        }
        #pragma unroll
        for (int nf = 0; nf < 19; ++nf) {
            int c = p * 304 + nf * 16 + col;
            if (c < 602) {
                #pragma unroll
                for (int r = 0; r < 4; ++r)
                    QW[(size_t)(re0 + r) * 608 + c] = f2bf(acc[nf][r]);
            }
        }
    }
}

// ---------- k_node: flash streaming, 1 wave/node, 2-edge pipeline; QW/Xagg bf16 ----------
__global__ __launch_bounds__(256) void k_node(
        const float* __restrict__ src_h, const float* __restrict__ efeat,
        const float* __restrict__ td,
        const float* __restrict__ time_w, const float* __restrict__ time_b,
        const unsigned short* __restrict__ QW, const int* __restrict__ off,
        unsigned short* __restrict__ Xagg) {
    const int lane = threadIdx.x & 63;
    const int n = blockIdx.x * 4 + (threadIdx.x >> 6);
    const int r0 = off[n], cnt = off[n + 1] - r0;
    unsigned short* __restrict__ xo = Xagg + (size_t)n * 600;
    if (cnt <= 0) {
        #pragma unroll
        for (int s = 0; s < 5; ++s) {
            int cc = s * 64 + lane;
            if (cc < 300) { xo[cc] = 0; xo[300 + cc] = 0; }
        }
        return;
    }
    float qw0[5], qw1[5];
    #pragma unroll
    for (int s = 0; s < 5; ++s) {
        int cc = s * 64 + lane;
        qw0[s] = (cc < 300) ? bf2f(QW[(size_t)n * 608 + cc])       : 0.f;
        qw1[s] = (cc < 300) ? bf2f(QW[(size_t)n * 608 + 300 + cc]) : 0.f;
    }
    const float B0 = bf2f(QW[(size_t)n * 608 + 600]);
    const float B1 = bf2f(QW[(size_t)n * 608 + 601]);
    float tw3 = 0.f, tb3 = 0.f, tw4 = 0.f, tb4 = 0.f;
    if (lane >= 8) { tw3 = time_w[lane - 8]; tb3 = time_b[lane - 8]; }
    if (lane < 44) { tw4 = time_w[56 + lane]; tb4 = time_b[56 + lane]; }

    auto LOADX = [&](float* x, int r) {
        const float* __restrict__ sr = src_h + (size_t)r * 100;
        const float* __restrict__ er = efeat + (size_t)r * 100;
        const float tdv = td[r];
        x[0] = sr[lane];
        x[1] = (lane < 36) ? sr[64 + lane] : er[lane - 36];
        x[2] = er[28 + lane];
        x[3] = (lane < 8) ? er[92 + lane] : __cosf(fmaf(tdv, tw3, tb3));
        x[4] = (lane < 44) ? __cosf(fmaf(tdv, tw4, tb4)) : 0.f;
    };

    float m0 = -1e30f, m1 = -1e30f, sum0 = 0.f, sum1 = 0.f;
    float a0[5] = {0.f, 0.f, 0.f, 0.f, 0.f}, a1[5] = {0.f, 0.f, 0.f, 0.f, 0.f};

    auto UPDATE = [&](float l0, float l1, const float* x) {
        l0 = l0 > 0.f ? l0 : 0.2f * l0;
        l1 = l1 > 0.f ? l1 : 0.2f * l1;
        if (l0 <= m0 && l1 <= m1) {          // wave-uniform fast path (r == 1 exactly)
            float w0 = __expf(l0 - m0), w1 = __expf(l1 - m1);
            sum0 += w0; sum1 += w1;
            #pragma unroll
            for (int s = 0; s < 5; ++s) {
                a0[s] = fmaf(w0, x[s], a0[s]);
                a1[s] = fmaf(w1, x[s], a1[s]);
            }
        } else {
            float m0n = fmaxf(m0, l0), m1n = fmaxf(m1, l1);
            float r0f = __expf(m0 - m0n), r1f = __expf(m1 - m1n);
            float w0 = __expf(l0 - m0n),  w1 = __expf(l1 - m1n);
            sum0 = fmaf(sum0, r0f, w0);
            sum1 = fmaf(sum1, r1f, w1);
            #pragma unroll
            for (int s = 0; s < 5; ++s) {
                a0[s] = fmaf(a0[s], r0f, w0 * x[s]);
                a1[s] = fmaf(a1[s], r1f, w1 * x[s]);
            }
            m0 = m0n; m1 = m1n;
        }
    };

    float xA[5], xB[5], xC[5], xD[5];
    int i = 0;
    if (cnt >= 2) {
        LOADX(xA, r0); LOADX(xB, r0 + 1);
        for (; i + 2 <= cnt; i += 2) {
            float pA0 = 0.f, pA1 = 0.f, pB0 = 0.f, pB1 = 0.f;
            #pragma unroll
            for (int s = 0; s < 5; ++s) {
                pA0 = fmaf(xA[s], qw0[s], pA0); pA1 = fmaf(xA[s], qw1[s], pA1);
                pB0 = fmaf(xB[s], qw0[s], pB0); pB1 = fmaf(xB[s], qw1[s], pB1);
            }
            #pragma unroll
            for (int sh = 1; sh < 64; sh <<= 1) {
                pA0 += __shfl_xor(pA0, sh); pA1 += __shfl_xor(pA1, sh);
                pB0 += __shfl_xor(pB0, sh); pB1 += __shfl_xor(pB1, sh);
            }
            if (i + 2 < cnt) LOADX(xC, r0 + i + 2);
            if (i + 3 < cnt) LOADX(xD, r0 + i + 3);
            UPDATE(pA0 + B0, pA1 + B1, xA);
            UPDATE(pB0 + B0, pB1 + B1, xB);
            #pragma unroll
            for (int s = 0; s < 5; ++s) { xA[s] = xC[s]; xB[s] = xD[s]; }
        }
    } else {
        LOADX(xA, r0);
    }
    if (i < cnt) {
        float p0 = 0.f, p1 = 0.f;
        #pragma unroll
        for (int s = 0; s < 5; ++s) {
            p0 = fmaf(xA[s], qw0[s], p0);
            p1 = fmaf(xA[s], qw1[s], p1);
        }
        #pragma unroll
        for (int sh = 1; sh < 64; sh <<= 1) {
            p0 += __shfl_xor(p0, sh); p1 += __shfl_xor(p1, sh);
        }
        UPDATE(p0 + B0, p1 + B1, xA);
    }
    const float inv0 = 1.f / sum0, inv1 = 1.f / sum1;
    #pragma unroll
    for (int s = 0; s < 5; ++s) {
        int cc = s * 64 + lane;
        if (cc < 300) {
            xo[cc]       = f2bf(a0[s] * inv0);
            xo[300 + cc] = f2bf(a1[s] * inv1);
        }
    }
}

// ---------- k_aggv (MFMA): agg = Xagg(bf16) @ Wbig + has*b_v ----------
__global__ __launch_bounds__(256, 1) void k_aggv(
        const unsigned short* __restrict__ Xagg, const unsigned short* __restrict__ Bv,
        const float* __restrict__ wkv_b, const int* __restrict__ off,
        float* __restrict__ agg) {
    __shared__ alignas(16) unsigned short Bs[10752];
    const int t = threadIdx.x, lane = t & 63;
    const int g = blockIdx.x * 4 + (t >> 6);
    const int col = lane & 15, slice = lane >> 4;
    const int row = g * 16 + col;

    short8b af[21];
    {
        const unsigned short* __restrict__ xr = Xagg + (size_t)row * 600;
        #pragma unroll
        for (int kc = 0; kc < 21; ++kc) {
            int j0 = kc * 32 + slice * 8;
            if (j0 + 8 <= 600) {
                af[kc] = *(const short8b*)(xr + j0);     // direct bf16 load (16B aligned)
            } else {
                short8b z; 
                #pragma unroll
                for (int q = 0; q < 8; ++q) z[q] = 0;
                af[kc] = z;
            }
        }
    }
    f32x4 acc[7];
    #pragma unroll
    for (int nf = 0; nf < 7; ++nf) acc[nf] = (f32x4){0.f, 0.f, 0.f, 0.f};

    #pragma unroll
    for (int slab = 0; slab < 7; ++slab) {
        {
            const float4* __restrict__ ws4 = (const float4*)Bv + (size_t)slab * 1344;
            float4* __restrict__ wd = (float4*)Bs;
            #pragma unroll
            for (int i = 0; i < 5; ++i) wd[i * 256 + t] = ws4[i * 256 + t];
            if (t < 64) wd[1280 + t] = ws4[1280 + t];
        }
        __syncthreads();
        #pragma unroll
        for (int kl = 0; kl < 3; ++kl) {
            const int kc = slab * 3 + kl;
            #pragma unroll
            for (int nf = 0; nf < 7; ++nf) {
                short8b w = *(const short8b*)(&Bs[(size_t)((kl * 7 + nf) * 64 + lane) * 8]);
                acc[nf] = __builtin_amdgcn_mfma_f32_16x16x32_bf16(af[kc], w, acc[nf], 0, 0, 0);
            }
        }
        __syncthreads();
    }
    const int re0 = g * 16 + (slice << 2);
    #pragma unroll
    for (int nf = 0; nf < 7; ++nf) {
        int o = nf * 16 + col;
        if (o < 100) {
            float bv = wkv_b[100 + o];
            #pragma unroll
            for (int r = 0; r < 4; ++r) {
                int node = re0 + r;
                bool has = off[node + 1] > off[node];
                agg[(size_t)node * 100 + o] = acc[nf][r] + (has ? bv : 0.f);
            }
        }
    }
}

// ---------- out proj + relu + layernorm: 8 nodes/block, coalesced wout_t ----------
__global__ __launch_bounds__(128) void k_out(const float* __restrict__ agg,
                                             const float* __restrict__ dst_h,
                                             const float* __restrict__ wout_t,
                                             const float* __restrict__ wout_b,
                                             const float* __restrict__ ln_g,
                                             const float* __restrict__ ln_b,
                                             float* __restrict__ out) {
    __shared__ float Fs[8][200];
    __shared__ float red[8][128];
    const int n0 = blockIdx.x * 8, t = threadIdx.x;
    for (int idx = t; idx < 1600; idx += 128) {
        int n = idx / 200, i = idx % 200;
        Fs[n][i] = (i < 100) ? agg[(size_t)(n0 + n) * 100 + i]
                             : dst_h[(size_t)(n0 + n) * 100 + (i - 100)];
    }
    __syncthreads();
    float v[8] = {0.f, 0.f, 0.f, 0.f, 0.f, 0.f, 0.f, 0.f};
    if (t < 100) {
        float b = wout_b[t];
        #pragma unroll
        for (int n = 0; n < 8; ++n) v[n] = b;
        for (int i = 0; i < 200; ++i) {
            float w = wout_t[i * 100 + t];
            #pragma unroll
            for (int n = 0; n < 8; ++n) v[n] = fmaf(Fs[n][i], w, v[n]);
        }
        #pragma unroll
        for (int n = 0; n < 8; ++n) v[n] = fmaxf(v[n], 0.f);
    }
    #pragma unroll
    for (int n = 0; n < 8; ++n) red[n][t] = (t < 100) ? v[n] : 0.f;
    __syncthreads();
    for (int s = 64; s > 0; s >>= 1) {
        if (t < s) {
            #pragma unroll
            for (int n = 0; n < 8; ++n) red[n][t] += red[n][t + s];
        }
        __syncthreads();
    }
    float mu[8];
    #pragma unroll
    for (int n = 0; n < 8; ++n) mu[n] = red[n][0] * 0.01f;
    __syncthreads();
    #pragma unroll
    for (int n = 0; n < 8; ++n) {
        float dv = (t < 100) ? (v[n] - mu[n]) : 0.f;
        red[n][t] = dv * dv;
    }
    __syncthreads();
    for (int s = 64; s > 0; s >>= 1) {
        if (t < s) {
            #pragma unroll
            for (int n = 0; n < 8; ++n) red[n][t] += red[n][t + s];
        }
        __syncthreads();
    }
    if (t < 100) {
        #pragma unroll
        for (int n = 0; n < 8; ++n) {
            float var = red[n][0] * 0.01f;
            out[(size_t)(n0 + n) * 100 + t] =
                (v[n] - mu[n]) * rsqrtf(var + LN_EPS) * ln_g[t] + ln_b[t];
        }
    }
}

extern "C" void kernel_launch(void* const* d_in, const int* in_sizes, int n_in,
                              void* d_out, int out_size, void* d_ws, size_t ws_size,
                              hipStream_t stream) {
    const float* dst_h   = (const float*)d_in[0];
    const float* src_h   = (const float*)d_in[1];
    const float* efeat   = (const float*)d_in[2];
    const float* td      = (const float*)d_in[3];
    const int*   edst    = (const int*)  d_in[4];
    const float* time_w  = (const float*)d_in[5];
    const float* time_b  = (const float*)d_in[6];
    const float* wq_w    = (const float*)d_in[7];
    const float* wq_b    = (const float*)d_in[8];
    const float* wkv_w   = (const float*)d_in[9];
    const float* wkv_b   = (const float*)d_in[10];
    const float* wout_w  = (const float*)d_in[11];
    const float* wout_b  = (const float*)d_in[12];
    const float* ln_g    = (const float*)d_in[13];
    const float* ln_b    = (const float*)d_in[14];
    float* out = (float*)d_out;

    char* ws = (char*)d_ws;
    size_t off = 0;
    auto carve = [&](size_t bytes) { char* p = ws + off; off = (off + bytes + 255) & ~(size_t)255; return p; };
    unsigned short* QW    = (unsigned short*)carve((size_t)N_DST * 608 * 2);
    unsigned short* Xagg  = (unsigned short*)carve((size_t)N_DST * 600 * 2);
    float*          agg   = (float*)carve((size_t)N_DST * 100 * 4);
    float*          C2    = (float*)carve(602 * 4);
    unsigned short* Bq    = (unsigned short*)carve(77824 * 2);
    unsigned short* Bv    = (unsigned short*)carve(75264 * 2);
    float*          woutT = (float*)carve(20000 * 4);
    float*          zq    = (float*)carve(100 * 4);
    int*            offs  = (int*)carve((size_t)(N_DST + 1) * 4);

    k_prep<<<(95364 + 255) / 256, 256, 0, stream>>>(wkv_w, wq_w, wq_b, time_b, wout_w,
                                                    zq, woutT, Bv);
    k_precomp<<<(78426 + 255) / 256, 256, 0, stream>>>(wq_w, wkv_w, wkv_b, zq, Bq, C2);
    k_offsets<<<(N_DST + 1 + 255) / 256, 256, 0, stream>>>(edst, offs);
    k_qw<<<N_DST / 64, 256, 0, stream>>>(dst_h, Bq, C2, QW);
    k_node<<<N_DST / 4, 256, 0, stream>>>(src_h, efeat, td, time_w, time_b,
                                          QW, offs, Xagg);
    k_aggv<<<N_DST / 64, 256, 0, stream>>>(Xagg, Bv, wkv_b, offs, agg);
    k_out<<<N_DST / 8, 128, 0, stream>>>(agg, dst_h, woutT, wout_b, ln_g, ln_b, out);
}

// Round 27
// 301.588 us; speedup vs baseline: 1.1297x; 1.0414x over previous
//
#include <hip/hip_runtime.h>
#include <math.h>

#define N_DST   32768
#define N_EDGE  524288
#define LN_EPS  1e-5f

typedef __attribute__((ext_vector_type(8))) short short8b;   // 8 bf16 (4 VGPR)
typedef __attribute__((ext_vector_type(4))) float f32x4;

static __device__ __forceinline__ unsigned short f2bf(float f) {
    unsigned u = __float_as_uint(f);
    u += 0x7fff + ((u >> 16) & 1);          // round-to-nearest-even
    return (unsigned short)(u >> 16);
}
static __device__ __forceinline__ float bf2f(unsigned short s) {
    return __uint_as_float(((unsigned)s) << 16);
}

// ---------- prep: zq, wout^T, Bv pack (block-diag V weights -> MFMA B-frag order) ----------
__global__ void k_prep(const float* __restrict__ wkv_w, const float* __restrict__ wq_w,
                       const float* __restrict__ wq_b, const float* __restrict__ time_b,
                       const float* __restrict__ wout_w,
                       float* __restrict__ zq, float* __restrict__ wout_t,
                       unsigned short* __restrict__ Bv) {
    int idx = blockIdx.x * 256 + threadIdx.x;
    if (idx < 100) {
        float acc = wq_b[idx];
        for (int j = 0; j < 100; ++j)
            acc += cosf(time_b[j]) * wq_w[idx * 200 + 100 + j];
        zq[idx] = acc;
    } else if (idx < 20100) {
        int r = idx - 100;                      // wout_t[i][o] = wout_w[o][i]
        wout_t[r] = wout_w[(size_t)(r % 100) * 200 + r / 100];
    } else if (idx < 95364) {
        int r2 = idx - 20100;
        int jj = r2 & 7, l = (r2 >> 3) & 63, nf = (r2 >> 9) % 7, kc = r2 / 3584;
        int j = kc * 32 + ((l >> 4) << 3) + jj;
        int o = nf * 16 + (l & 15);
        float v = (j < 600 && o < 100 && (j / 300 == o / 50))
                  ? wkv_w[(size_t)(100 + o) * 300 + (j % 300)] : 0.f;
        Bv[r2] = f2bf(v);
    }
}

// ---------- k_precomp: QW-map computed DIRECTLY in MFMA B-frag packed order ----------
__global__ void k_precomp(const float* __restrict__ wq_w, const float* __restrict__ wkv_w,
                          const float* __restrict__ wkv_b, const float* __restrict__ zq,
                          unsigned short* __restrict__ Bq, float* __restrict__ C2) {
    int idx = blockIdx.x * 256 + threadIdx.x;
    if (idx < 77824) {
        int jj = idx & 7, l = (idx >> 3) & 63, nf = (idx >> 9) % 19, kcp = idx / 9728;
        int kc = kcp & 3, p = kcp >> 2;
        int i = kc * 32 + ((l >> 4) << 3) + jj;
        int j = p * 304 + nf * 16 + (l & 15);
        float acc = 0.f;
        if (i < 100 && j < 602) {
            if (j < 600) {
                int h = j / 300, cc = j % 300;
                const float* __restrict__ wq = wq_w + (size_t)(h * 50) * 200 + i;
                const float* __restrict__ wk = wkv_w + (size_t)(h * 50) * 300 + cc;
                #pragma unroll 10
                for (int d = 0; d < 50; ++d)
                    acc = fmaf(wq[(size_t)d * 200], wk[(size_t)d * 300], acc);
            } else {
                int h = j - 600;
                const float* __restrict__ wq = wq_w + (size_t)(h * 50) * 200 + i;
                for (int d = 0; d < 50; ++d)
                    acc = fmaf(wq[(size_t)d * 200], wkv_b[h * 50 + d], acc);
            }
        }
        Bq[idx] = f2bf(acc);
    } else if (idx < 78426) {
        int j = idx - 77824;
        float acc = 0.f;
        if (j < 600) {
            int h = j / 300, cc = j % 300;
            for (int d = 0; d < 50; ++d)
                acc = fmaf(zq[h * 50 + d], wkv_w[(size_t)(h * 50 + d) * 300 + cc], acc);
        } else {
            int h = j - 600;
            for (int d = 0; d < 50; ++d)
                acc = fmaf(zq[h * 50 + d], wkv_b[h * 50 + d], acc);
        }
        C2[j] = acc;
    }
}

// ---------- CSR offsets via binary search over sorted edge_dst ----------
__global__ void k_offsets(const int* __restrict__ dst, int* __restrict__ off) {
    int n = blockIdx.x * 256 + threadIdx.x;
    if (n > N_DST) return;
    int lo = 0, hi = N_EDGE;
    while (lo < hi) {
        int mid = (lo + hi) >> 1;
        if (dst[mid] < n) lo = mid + 1; else hi = mid;
    }
    off[n] = lo;
}

// ---------- k_qw (MFMA): QW[32768x602] = dst_h @ A2 + C2, stored as BF16 ----------
__global__ __launch_bounds__(256, 1) void k_qw(
        const float* __restrict__ dst_h, const unsigned short* __restrict__ Bq,
        const float* __restrict__ C2, unsigned short* __restrict__ QW) {
    __shared__ alignas(16) unsigned short Bs[9728];
    const int t = threadIdx.x, lane = t & 63;
    const int g = blockIdx.x * 4 + (t >> 6);
    const int col = lane & 15, slice = lane >> 4;
    const int row = g * 16 + col;

    short8b af[4];
    {
        const float* __restrict__ dr = dst_h + (size_t)row * 100;
        #pragma unroll
        for (int kc = 0; kc < 4; ++kc) {
            int k0 = kc * 32 + slice * 8;
            float4 xa = make_float4(0.f, 0.f, 0.f, 0.f), xb = xa;
            if (k0 + 8 <= 100) { xa = *(const float4*)(dr + k0); xb = *(const float4*)(dr + k0 + 4); }
            else if (k0 < 100)  { xa = *(const float4*)(dr + k0); }
            short8b a;
            a[0] = (short)f2bf(xa.x); a[1] = (short)f2bf(xa.y);
            a[2] = (short)f2bf(xa.z); a[3] = (short)f2bf(xa.w);
            a[4] = (short)f2bf(xb.x); a[5] = (short)f2bf(xb.y);
            a[6] = (short)f2bf(xb.z); a[7] = (short)f2bf(xb.w);
            af[kc] = a;
        }
    }
    const int re0 = g * 16 + (slice << 2);
    #pragma unroll
    for (int p = 0; p < 2; ++p) {
        f32x4 acc[19];
        #pragma unroll
        for (int nf = 0; nf < 19; ++nf) {
            int c = p * 304 + nf * 16 + col;
            float b = (c < 602) ? C2[c] : 0.f;
            acc[nf] = (f32x4){b, b, b, b};
        }
        #pragma unroll
        for (int kc = 0; kc < 4; ++kc) {
            {
                const float4* __restrict__ ws4 = (const float4*)Bq + (size_t)(p * 4 + kc) * 1216;
                float4* __restrict__ wd = (float4*)Bs;
                #pragma unroll
                for (int i = 0; i < 4; ++i) wd[i * 256 + t] = ws4[i * 256 + t];
                if (t < 192) wd[1024 + t] = ws4[1024 + t];
            }
            __syncthreads();
            #pragma unroll
            for (int nf = 0; nf < 19; ++nf) {
                short8b w = *(const short8b*)(&Bs[(size_t)(nf * 64 + lane) * 8]);
                acc[nf] = __builtin_amdgcn_mfma_f32_16x16x32_bf16(af[kc], w, acc[nf], 0, 0, 0);
            }
            __syncthreads();
        }
        #pragma unroll
        for (int nf = 0; nf < 19; ++nf) {
            int c = p * 304 + nf * 16 + col;
            if (c < 602) {
                #pragma unroll
                for (int r = 0; r < 4; ++r)
                    QW[(size_t)(re0 + r) * 608 + c] = f2bf(acc[nf][r]);
            }
        }
    }
}

// ---------- k_node: 16-LANES-PER-EDGE (4 edges/wave concurrent), shared wave-max m ----------
// Per iteration: group g handles edge i+g. 4-level group reduce; one UPDATE stream serves
// 4 edges; shared m makes the final cross-group merge a pure shfl-add (no rescale).
__global__ __launch_bounds__(256) void k_node(
        const float* __restrict__ src_h, const float* __restrict__ efeat,
        const float* __restrict__ td,
        const float* __restrict__ time_w, const float* __restrict__ time_b,
        const unsigned short* __restrict__ QW, const int* __restrict__ off,
        unsigned short* __restrict__ Xagg) {
    const int lane = threadIdx.x & 63;
    const int grp = lane >> 4, li = lane & 15;
    const int n = blockIdx.x * 4 + (threadIdx.x >> 6);
    const int r0 = off[n], cnt = off[n + 1] - r0;
    unsigned short* __restrict__ xo = Xagg + (size_t)n * 600;
    if (cnt <= 0) {
        #pragma unroll
        for (int s = 0; s < 19; ++s) {
            if ((s & 3) == grp) {
                int cc = s * 16 + li;
                if (cc < 300) { xo[cc] = 0; xo[300 + cc] = 0; }
            }
        }
        return;
    }
    // per-lane QW slots: cc = 16s + li
    float qw0[19], qw1[19];
    #pragma unroll
    for (int s = 0; s < 19; ++s) {
        int cc = s * 16 + li;
        qw0[s] = (cc < 300) ? bf2f(QW[(size_t)n * 608 + cc])       : 0.f;
        qw1[s] = (cc < 300) ? bf2f(QW[(size_t)n * 608 + 300 + cc]) : 0.f;
    }
    const float B0 = bf2f(QW[(size_t)n * 608 + 600]);
    const float B1 = bf2f(QW[(size_t)n * 608 + 601]);
    // time constants for slots 12..18 (cc-200 = 16s+li-200)
    float tWc[7], tBc[7];
    #pragma unroll
    for (int q = 0; q < 7; ++q) {
        int j = (12 + q) * 16 + li - 200;
        bool v = (j >= 0 && j < 100);
        tWc[q] = v ? time_w[j] : 0.f;
        tBc[q] = v ? time_b[j] : 0.f;
    }

    float m0 = -1e30f, m1 = -1e30f, sum0 = 0.f, sum1 = 0.f;
    float a0[19], a1[19];
    #pragma unroll
    for (int s = 0; s < 19; ++s) { a0[s] = 0.f; a1[s] = 0.f; }

    for (int i = 0; i < cnt; i += 4) {
        const int e = i + grp;
        const bool valid = (e < cnt);
        const int r = r0 + (valid ? e : 0);
        float x[19];
        {
            const float* __restrict__ sr = src_h + (size_t)r * 100;
            const float* __restrict__ er = efeat + (size_t)r * 100;
            const float tdv = valid ? td[r] : 0.f;
            #pragma unroll
            for (int s = 0; s < 19; ++s) {
                int cc = s * 16 + li;
                float v;
                if (s < 6)        v = sr[cc];
                else if (s == 6)  v = (li < 4) ? sr[96 + li] : er[li - 4];
                else if (s < 12)  v = er[cc - 100];
                else if (s == 12) v = (li < 8) ? er[92 + li]
                                               : __cosf(fmaf(tdv, tWc[0], tBc[0]));
                else if (s < 18)  v = __cosf(fmaf(tdv, tWc[s - 12], tBc[s - 12]));
                else              v = (li < 12) ? __cosf(fmaf(tdv, tWc[6], tBc[6])) : 0.f;
                x[s] = valid ? v : 0.f;
            }
        }
        float p0 = 0.f, p1 = 0.f;
        #pragma unroll
        for (int s = 0; s < 19; ++s) {
            p0 = fmaf(x[s], qw0[s], p0);
            p1 = fmaf(x[s], qw1[s], p1);
        }
        #pragma unroll
        for (int sh = 1; sh < 16; sh <<= 1) {       // 4-level group reduce
            p0 += __shfl_xor(p0, sh);
            p1 += __shfl_xor(p1, sh);
        }
        float l0 = p0 + B0, l1 = p1 + B1;
        l0 = l0 > 0.f ? l0 : 0.2f * l0;
        l1 = l1 > 0.f ? l1 : 0.2f * l1;
        if (!valid) { l0 = -1e30f; l1 = -1e30f; }   // w -> 0 exactly
        float mx0 = l0, mx1 = l1;                   // wave max across 4 groups
        mx0 = fmaxf(mx0, __shfl_xor(mx0, 16)); mx1 = fmaxf(mx1, __shfl_xor(mx1, 16));
        mx0 = fmaxf(mx0, __shfl_xor(mx0, 32)); mx1 = fmaxf(mx1, __shfl_xor(mx1, 32));
        if (mx0 <= m0 && mx1 <= m1) {               // fast path: no rescale
            float w0 = __expf(l0 - m0), w1 = __expf(l1 - m1);
            sum0 += w0; sum1 += w1;
            #pragma unroll
            for (int s = 0; s < 19; ++s) {
                a0[s] = fmaf(w0, x[s], a0[s]);
                a1[s] = fmaf(w1, x[s], a1[s]);
            }
        } else {
            float m0n = fmaxf(m0, mx0), m1n = fmaxf(m1, mx1);
            float r0f = __expf(m0 - m0n), r1f = __expf(m1 - m1n);
            float w0 = __expf(l0 - m0n),  w1 = __expf(l1 - m1n);
            sum0 = fmaf(sum0, r0f, w0);
            sum1 = fmaf(sum1, r1f, w1);
            #pragma unroll
            for (int s = 0; s < 19; ++s) {
                a0[s] = fmaf(a0[s], r0f, w0 * x[s]);
                a1[s] = fmaf(a1[s], r1f, w1 * x[s]);
            }
            m0 = m0n; m1 = m1n;
        }
    }
    // cross-group merge: shared m -> pure adds
    #pragma unroll
    for (int s = 0; s < 19; ++s) {
        a0[s] += __shfl_xor(a0[s], 16); a0[s] += __shfl_xor(a0[s], 32);
        a1[s] += __shfl_xor(a1[s], 16); a1[s] += __shfl_xor(a1[s], 32);
    }
    sum0 += __shfl_xor(sum0, 16); sum0 += __shfl_xor(sum0, 32);
    sum1 += __shfl_xor(sum1, 16); sum1 += __shfl_xor(sum1, 32);
    const float inv0 = 1.f / sum0, inv1 = 1.f / sum1;
    #pragma unroll
    for (int s = 0; s < 19; ++s) {
        if ((s & 3) == grp) {                       // distribute writes across groups
            int cc = s * 16 + li;
            if (cc < 300) {
                xo[cc]       = f2bf(a0[s] * inv0);
                xo[300 + cc] = f2bf(a1[s] * inv1);
            }
        }
    }
}

// ---------- k_aggv (MFMA): agg = Xagg(bf16) @ Wbig + has*b_v ----------
__global__ __launch_bounds__(256, 1) void k_aggv(
        const unsigned short* __restrict__ Xagg, const unsigned short* __restrict__ Bv,
        const float* __restrict__ wkv_b, const int* __restrict__ off,
        float* __restrict__ agg) {
    __shared__ alignas(16) unsigned short Bs[10752];
    const int t = threadIdx.x, lane = t & 63;
    const int g = blockIdx.x * 4 + (t >> 6);
    const int col = lane & 15, slice = lane >> 4;
    const int row = g * 16 + col;

    short8b af[21];
    {
        const unsigned short* __restrict__ xr = Xagg + (size_t)row * 600;
        #pragma unroll
        for (int kc = 0; kc < 21; ++kc) {
            int j0 = kc * 32 + slice * 8;
            if (j0 + 8 <= 600) {
                af[kc] = *(const short8b*)(xr + j0);
            } else {
                short8b z;
                #pragma unroll
                for (int q = 0; q < 8; ++q) z[q] = 0;
                af[kc] = z;
            }
        }
    }
    f32x4 acc[7];
    #pragma unroll
    for (int nf = 0; nf < 7; ++nf) acc[nf] = (f32x4){0.f, 0.f, 0.f, 0.f};

    #pragma unroll
    for (int slab = 0; slab < 7; ++slab) {
        {
            const float4* __restrict__ ws4 = (const float4*)Bv + (size_t)slab * 1344;
            float4* __restrict__ wd = (float4*)Bs;
            #pragma unroll
            for (int i = 0; i < 5; ++i) wd[i * 256 + t] = ws4[i * 256 + t];
            if (t < 64) wd[1280 + t] = ws4[1280 + t];
        }
        __syncthreads();
        #pragma unroll
        for (int kl = 0; kl < 3; ++kl) {
            const int kc = slab * 3 + kl;
            #pragma unroll
            for (int nf = 0; nf < 7; ++nf) {
                short8b w = *(const short8b*)(&Bs[(size_t)((kl * 7 + nf) * 64 + lane) * 8]);
                acc[nf] = __builtin_amdgcn_mfma_f32_16x16x32_bf16(af[kc], w, acc[nf], 0, 0, 0);
            }
        }
        __syncthreads();
    }
    const int re0 = g * 16 + (slice << 2);
    #pragma unroll
    for (int nf = 0; nf < 7; ++nf) {
        int o = nf * 16 + col;
        if (o < 100) {
            float bv = wkv_b[100 + o];
            #pragma unroll
            for (int r = 0; r < 4; ++r) {
                int node = re0 + r;
                bool has = off[node + 1] > off[node];
                agg[(size_t)node * 100 + o] = acc[nf][r] + (has ? bv : 0.f);
            }
        }
    }
}

// ---------- out proj + relu + layernorm: 8 nodes/block, coalesced wout_t ----------
__global__ __launch_bounds__(128) void k_out(const float* __restrict__ agg,
                                             const float* __restrict__ dst_h,
                                             const float* __restrict__ wout_t,
                                             const float* __restrict__ wout_b,
                                             const float* __restrict__ ln_g,
                                             const float* __restrict__ ln_b,
                                             float* __restrict__ out) {
    __shared__ float Fs[8][200];
    __shared__ float red[8][128];
    const int n0 = blockIdx.x * 8, t = threadIdx.x;
    for (int idx = t; idx < 1600; idx += 128) {
        int n = idx / 200, i = idx % 200;
        Fs[n][i] = (i < 100) ? agg[(size_t)(n0 + n) * 100 + i]
                             : dst_h[(size_t)(n0 + n) * 100 + (i - 100)];
    }
    __syncthreads();
    float v[8] = {0.f, 0.f, 0.f, 0.f, 0.f, 0.f, 0.f, 0.f};
    if (t < 100) {
        float b = wout_b[t];
        #pragma unroll
        for (int n = 0; n < 8; ++n) v[n] = b;
        for (int i = 0; i < 200; ++i) {
            float w = wout_t[i * 100 + t];
            #pragma unroll
            for (int n = 0; n < 8; ++n) v[n] = fmaf(Fs[n][i], w, v[n]);
        }
        #pragma unroll
        for (int n = 0; n < 8; ++n) v[n] = fmaxf(v[n], 0.f);
    }
    #pragma unroll
    for (int n = 0; n < 8; ++n) red[n][t] = (t < 100) ? v[n] : 0.f;
    __syncthreads();
    for (int s = 64; s > 0; s >>= 1) {
        if (t < s) {
            #pragma unroll
            for (int n = 0; n < 8; ++n) red[n][t] += red[n][t + s];
        }
        __syncthreads();
    }
    float mu[8];
    #pragma unroll
    for (int n = 0; n < 8; ++n) mu[n] = red[n][0] * 0.01f;
    __syncthreads();
    #pragma unroll
    for (int n = 0; n < 8; ++n) {
        float dv = (t < 100) ? (v[n] - mu[n]) : 0.f;
        red[n][t] = dv * dv;
    }
    __syncthreads();
    for (int s = 64; s > 0; s >>= 1) {
        if (t < s) {
            #pragma unroll
            for (int n = 0; n < 8; ++n) red[n][t] += red[n][t + s];
        }
        __syncthreads();
    }
    if (t < 100) {
        #pragma unroll
        for (int n = 0; n < 8; ++n) {
            float var = red[n][0] * 0.01f;
            out[(size_t)(n0 + n) * 100 + t] =
                (v[n] - mu[n]) * rsqrtf(var + LN_EPS) * ln_g[t] + ln_b[t];
        }
    }
}

extern "C" void kernel_launch(void* const* d_in, const int* in_sizes, int n_in,
                              void* d_out, int out_size, void* d_ws, size_t ws_size,
                              hipStream_t stream) {
    const float* dst_h   = (const float*)d_in[0];
    const float* src_h   = (const float*)d_in[1];
    const float* efeat   = (const float*)d_in[2];
    const float* td      = (const float*)d_in[3];
    const int*   edst    = (const int*)  d_in[4];
    const float* time_w  = (const float*)d_in[5];
    const float* time_b  = (const float*)d_in[6];
    const float* wq_w    = (const float*)d_in[7];
    const float* wq_b    = (const float*)d_in[8];
    const float* wkv_w   = (const float*)d_in[9];
    const float* wkv_b   = (const float*)d_in[10];
    const float* wout_w  = (const float*)d_in[11];
    const float* wout_b  = (const float*)d_in[12];
    const float* ln_g    = (const float*)d_in[13];
    const float* ln_b    = (const float*)d_in[14];
    float* out = (float*)d_out;

    char* ws = (char*)d_ws;
    size_t off = 0;
    auto carve = [&](size_t bytes) { char* p = ws + off; off = (off + bytes + 255) & ~(size_t)255; return p; };
    unsigned short* QW    = (unsigned short*)carve((size_t)N_DST * 608 * 2);
    unsigned short* Xagg  = (unsigned short*)carve((size_t)N_DST * 600 * 2);
    float*          agg   = (float*)carve((size_t)N_DST * 100 * 4);
    float*          C2    = (float*)carve(602 * 4);
    unsigned short* Bq    = (unsigned short*)carve(77824 * 2);
    unsigned short* Bv    = (unsigned short*)carve(75264 * 2);
    float*          woutT = (float*)carve(20000 * 4);
    float*          zq    = (float*)carve(100 * 4);
    int*            offs  = (int*)carve((size_t)(N_DST + 1) * 4);

    k_prep<<<(95364 + 255) / 256, 256, 0, stream>>>(wkv_w, wq_w, wq_b, time_b, wout_w,
                                                    zq, woutT, Bv);
    k_precomp<<<(78426 + 255) / 256, 256, 0, stream>>>(wq_w, wkv_w, wkv_b, zq, Bq, C2);
    k_offsets<<<(N_DST + 1 + 255) / 256, 256, 0, stream>>>(edst, offs);
    k_qw<<<N_DST / 64, 256, 0, stream>>>(dst_h, Bq, C2, QW);
    k_node<<<N_DST / 4, 256, 0, stream>>>(src_h, efeat, td, time_w, time_b,
                                          QW, offs, Xagg);
    k_aggv<<<N_DST / 64, 256, 0, stream>>>(Xagg, Bv, wkv_b, offs, agg);
    k_out<<<N_DST / 8, 128, 0, stream>>>(agg, dst_h, woutT, wout_b, ln_g, ln_b, out);
}

// Round 30
// 300.358 us; speedup vs baseline: 1.1343x; 1.0041x over previous
//
#include <hip/hip_runtime.h>
#include <math.h>

#define N_DST   32768
#define N_EDGE  524288
#define LN_EPS  1e-5f

typedef __attribute__((ext_vector_type(8))) short short8b;   // 8 bf16 (4 VGPR)
typedef __attribute__((ext_vector_type(4))) float f32x4;

static __device__ __forceinline__ unsigned short f2bf(float f) {
    unsigned u = __float_as_uint(f);
    u += 0x7fff + ((u >> 16) & 1);          // round-to-nearest-even
    return (unsigned short)(u >> 16);
}
static __device__ __forceinline__ float bf2f(unsigned short s) {
    return __uint_as_float(((unsigned)s) << 16);
}

// ---------- prep: zq, wout^T, Bv pack (block-diag V weights -> MFMA B-frag order) ----------
__global__ void k_prep(const float* __restrict__ wkv_w, const float* __restrict__ wq_w,
                       const float* __restrict__ wq_b, const float* __restrict__ time_b,
                       const float* __restrict__ wout_w,
                       float* __restrict__ zq, float* __restrict__ wout_t,
                       unsigned short* __restrict__ Bv) {
    int idx = blockIdx.x * 256 + threadIdx.x;
    if (idx < 100) {
        float acc = wq_b[idx];
        for (int j = 0; j < 100; ++j)
            acc += cosf(time_b[j]) * wq_w[idx * 200 + 100 + j];
        zq[idx] = acc;
    } else if (idx < 20100) {
        int r = idx - 100;                      // wout_t[i][o] = wout_w[o][i]
        wout_t[r] = wout_w[(size_t)(r % 100) * 200 + r / 100];
    } else if (idx < 95364) {
        int r2 = idx - 20100;
        int jj = r2 & 7, l = (r2 >> 3) & 63, nf = (r2 >> 9) % 7, kc = r2 / 3584;
        int j = kc * 32 + ((l >> 4) << 3) + jj;
        int o = nf * 16 + (l & 15);
        float v = (j < 600 && o < 100 && (j / 300 == o / 50))
                  ? wkv_w[(size_t)(100 + o) * 300 + (j % 300)] : 0.f;
        Bv[r2] = f2bf(v);
    }
}

// ---------- k_precomp: QW-map computed DIRECTLY in MFMA B-frag packed order ----------
__global__ void k_precomp(const float* __restrict__ wq_w, const float* __restrict__ wkv_w,
                          const float* __restrict__ wkv_b, const float* __restrict__ zq,
                          unsigned short* __restrict__ Bq, float* __restrict__ C2) {
    int idx = blockIdx.x * 256 + threadIdx.x;
    if (idx < 77824) {
        int jj = idx & 7, l = (idx >> 3) & 63, nf = (idx >> 9) % 19, kcp = idx / 9728;
        int kc = kcp & 3, p = kcp >> 2;
        int i = kc * 32 + ((l >> 4) << 3) + jj;
        int j = p * 304 + nf * 16 + (l & 15);
        float acc = 0.f;
        if (i < 100 && j < 602) {
            if (j < 600) {
                int h = j / 300, cc = j % 300;
                const float* __restrict__ wq = wq_w + (size_t)(h * 50) * 200 + i;
                const float* __restrict__ wk = wkv_w + (size_t)(h * 50) * 300 + cc;
                #pragma unroll 10
                for (int d = 0; d < 50; ++d)
                    acc = fmaf(wq[(size_t)d * 200], wk[(size_t)d * 300], acc);
            } else {
                int h = j - 600;
                const float* __restrict__ wq = wq_w + (size_t)(h * 50) * 200 + i;
                for (int d = 0; d < 50; ++d)
                    acc = fmaf(wq[(size_t)d * 200], wkv_b[h * 50 + d], acc);
            }
        }
        Bq[idx] = f2bf(acc);
    } else if (idx < 78426) {
        int j = idx - 77824;
        float acc = 0.f;
        if (j < 600) {
            int h = j / 300, cc = j % 300;
            for (int d = 0; d < 50; ++d)
                acc = fmaf(zq[h * 50 + d], wkv_w[(size_t)(h * 50 + d) * 300 + cc], acc);
        } else {
            int h = j - 600;
            for (int d = 0; d < 50; ++d)
                acc = fmaf(zq[h * 50 + d], wkv_b[h * 50 + d], acc);
        }
        C2[j] = acc;
    }
}

// ---------- CSR offsets via binary search over sorted edge_dst ----------
__global__ void k_offsets(const int* __restrict__ dst, int* __restrict__ off) {
    int n = blockIdx.x * 256 + threadIdx.x;
    if (n > N_DST) return;
    int lo = 0, hi = N_EDGE;
    while (lo < hi) {
        int mid = (lo + hi) >> 1;
        if (dst[mid] < n) lo = mid + 1; else hi = mid;
    }
    off[n] = lo;
}

// ---------- k_qw (MFMA): QW[32768x602] = dst_h @ A2 + C2, stored as BF16 ----------
__global__ __launch_bounds__(256, 1) void k_qw(
        const float* __restrict__ dst_h, const unsigned short* __restrict__ Bq,
        const float* __restrict__ C2, unsigned short* __restrict__ QW) {
    __shared__ alignas(16) unsigned short Bs[9728];
    const int t = threadIdx.x, lane = t & 63;
    const int g = blockIdx.x * 4 + (t >> 6);
    const int col = lane & 15, slice = lane >> 4;
    const int row = g * 16 + col;

    short8b af[4];
    {
        const float* __restrict__ dr = dst_h + (size_t)row * 100;
        #pragma unroll
        for (int kc = 0; kc < 4; ++kc) {
            int k0 = kc * 32 + slice * 8;
            float4 xa = make_float4(0.f, 0.f, 0.f, 0.f), xb = xa;
            if (k0 + 8 <= 100) { xa = *(const float4*)(dr + k0); xb = *(const float4*)(dr + k0 + 4); }
            else if (k0 < 100)  { xa = *(const float4*)(dr + k0); }
            short8b a;
            a[0] = (short)f2bf(xa.x); a[1] = (short)f2bf(xa.y);
            a[2] = (short)f2bf(xa.z); a[3] = (short)f2bf(xa.w);
            a[4] = (short)f2bf(xb.x); a[5] = (short)f2bf(xb.y);
            a[6] = (short)f2bf(xb.z); a[7] = (short)f2bf(xb.w);
            af[kc] = a;
        }
    }
    const int re0 = g * 16 + (slice << 2);
    #pragma unroll
    for (int p = 0; p < 2; ++p) {
        f32x4 acc[19];
        #pragma unroll
        for (int nf = 0; nf < 19; ++nf) {
            int c = p * 304 + nf * 16 + col;
            float b = (c < 602) ? C2[c] : 0.f;
            acc[nf] = (f32x4){b, b, b, b};
        }
        #pragma unroll
        for (int kc = 0; kc < 4; ++kc) {
            {
                const float4* __restrict__ ws4 = (const float4*)Bq + (size_t)(p * 4 + kc) * 1216;
                float4* __restrict__ wd = (float4*)Bs;
                #pragma unroll
                for (int i = 0; i < 4; ++i) wd[i * 256 + t] = ws4[i * 256 + t];
                if (t < 192) wd[1024 + t] = ws4[1024 + t];
            }
            __syncthreads();
            #pragma unroll
            for (int nf = 0; nf < 19; ++nf) {
                short8b w = *(const short8b*)(&Bs[(size_t)(nf * 64 + lane) * 8]);
                acc[nf] = __builtin_amdgcn_mfma_f32_16x16x32_bf16(af[kc], w, acc[nf], 0, 0, 0);
            }
            __syncthreads();
        }
        #pragma unroll
        for (int nf = 0; nf < 19; ++nf) {
            int c = p * 304 + nf * 16 + col;
            if (c < 602) {
                #pragma unroll
                for (int r = 0; r < 4; ++r)
                    QW[(size_t)(re0 + r) * 608 + c] = f2bf(acc[nf][r]);
            }
        }
    }
}

// ---------- k_node: 16-lanes-per-edge (round-27 proven) ----------
__global__ __launch_bounds__(256) void k_node(
        const float* __restrict__ src_h, const float* __restrict__ efeat,
        const float* __restrict__ td,
        const float* __restrict__ time_w, const float* __restrict__ time_b,
        const unsigned short* __restrict__ QW, const int* __restrict__ off,
        unsigned short* __restrict__ Xagg) {
    const int lane = threadIdx.x & 63;
    const int grp = lane >> 4, li = lane & 15;
    const int n = blockIdx.x * 4 + (threadIdx.x >> 6);
    const int r0 = off[n], cnt = off[n + 1] - r0;
    unsigned short* __restrict__ xo = Xagg + (size_t)n * 600;
    if (cnt <= 0) {
        #pragma unroll
        for (int s = 0; s < 19; ++s) {
            if ((s & 3) == grp) {
                int cc = s * 16 + li;
                if (cc < 300) { xo[cc] = 0; xo[300 + cc] = 0; }
            }
        }
        return;
    }
    float qw0[19], qw1[19];
    #pragma unroll
    for (int s = 0; s < 19; ++s) {
        int cc = s * 16 + li;
        qw0[s] = (cc < 300) ? bf2f(QW[(size_t)n * 608 + cc])       : 0.f;
        qw1[s] = (cc < 300) ? bf2f(QW[(size_t)n * 608 + 300 + cc]) : 0.f;
    }
    const float B0 = bf2f(QW[(size_t)n * 608 + 600]);
    const float B1 = bf2f(QW[(size_t)n * 608 + 601]);
    float tWc[7], tBc[7];
    #pragma unroll
    for (int q = 0; q < 7; ++q) {
        int j = (12 + q) * 16 + li - 200;
        bool v = (j >= 0 && j < 100);
        tWc[q] = v ? time_w[j] : 0.f;
        tBc[q] = v ? time_b[j] : 0.f;
    }

    float m0 = -1e30f, m1 = -1e30f, sum0 = 0.f, sum1 = 0.f;
    float a0[19], a1[19];
    #pragma unroll
    for (int s = 0; s < 19; ++s) { a0[s] = 0.f; a1[s] = 0.f; }

    for (int i = 0; i < cnt; i += 4) {
        const int e = i + grp;
        const bool valid = (e < cnt);
        const int r = r0 + (valid ? e : 0);
        float x[19];
        {
            const float* __restrict__ sr = src_h + (size_t)r * 100;
            const float* __restrict__ er = efeat + (size_t)r * 100;
            const float tdv = valid ? td[r] : 0.f;
            #pragma unroll
            for (int s = 0; s < 19; ++s) {
                int cc = s * 16 + li;
                float v;
                if (s < 6)        v = sr[cc];
                else if (s == 6)  v = (li < 4) ? sr[96 + li] : er[li - 4];
                else if (s < 12)  v = er[cc - 100];
                else if (s == 12) v = (li < 8) ? er[92 + li]
                                               : __cosf(fmaf(tdv, tWc[0], tBc[0]));
                else if (s < 18)  v = __cosf(fmaf(tdv, tWc[s - 12], tBc[s - 12]));
                else              v = (li < 12) ? __cosf(fmaf(tdv, tWc[6], tBc[6])) : 0.f;
                x[s] = valid ? v : 0.f;
            }
        }
        float p0 = 0.f, p1 = 0.f;
        #pragma unroll
        for (int s = 0; s < 19; ++s) {
            p0 = fmaf(x[s], qw0[s], p0);
            p1 = fmaf(x[s], qw1[s], p1);
        }
        #pragma unroll
        for (int sh = 1; sh < 16; sh <<= 1) {
            p0 += __shfl_xor(p0, sh);
            p1 += __shfl_xor(p1, sh);
        }
        float l0 = p0 + B0, l1 = p1 + B1;
        l0 = l0 > 0.f ? l0 : 0.2f * l0;
        l1 = l1 > 0.f ? l1 : 0.2f * l1;
        if (!valid) { l0 = -1e30f; l1 = -1e30f; }
        float mx0 = l0, mx1 = l1;
        mx0 = fmaxf(mx0, __shfl_xor(mx0, 16)); mx1 = fmaxf(mx1, __shfl_xor(mx1, 16));
        mx0 = fmaxf(mx0, __shfl_xor(mx0, 32)); mx1 = fmaxf(mx1, __shfl_xor(mx1, 32));
        if (mx0 <= m0 && mx1 <= m1) {
            float w0 = __expf(l0 - m0), w1 = __expf(l1 - m1);
            sum0 += w0; sum1 += w1;
            #pragma unroll
            for (int s = 0; s < 19; ++s) {
                a0[s] = fmaf(w0, x[s], a0[s]);
                a1[s] = fmaf(w1, x[s], a1[s]);
            }
        } else {
            float m0n = fmaxf(m0, mx0), m1n = fmaxf(m1, mx1);
            float r0f = __expf(m0 - m0n), r1f = __expf(m1 - m1n);
            float w0 = __expf(l0 - m0n),  w1 = __expf(l1 - m1n);
            sum0 = fmaf(sum0, r0f, w0);
            sum1 = fmaf(sum1, r1f, w1);
            #pragma unroll
            for (int s = 0; s < 19; ++s) {
                a0[s] = fmaf(a0[s], r0f, w0 * x[s]);
                a1[s] = fmaf(a1[s], r1f, w1 * x[s]);
            }
            m0 = m0n; m1 = m1n;
        }
    }
    #pragma unroll
    for (int s = 0; s < 19; ++s) {
        a0[s] += __shfl_xor(a0[s], 16); a0[s] += __shfl_xor(a0[s], 32);
        a1[s] += __shfl_xor(a1[s], 16); a1[s] += __shfl_xor(a1[s], 32);
    }
    sum0 += __shfl_xor(sum0, 16); sum0 += __shfl_xor(sum0, 32);
    sum1 += __shfl_xor(sum1, 16); sum1 += __shfl_xor(sum1, 32);
    const float inv0 = 1.f / sum0, inv1 = 1.f / sum1;
    #pragma unroll
    for (int s = 0; s < 19; ++s) {
        if ((s & 3) == grp) {
            int cc = s * 16 + li;
            if (cc < 300) {
                xo[cc]       = f2bf(a0[s] * inv0);
                xo[300 + cc] = f2bf(a1[s] * inv1);
            }
        }
    }
}

// ---------- k_aggv (MFMA): agg = Xagg(bf16) @ Wbig + has*b_v ----------
__global__ __launch_bounds__(256, 1) void k_aggv(
        const unsigned short* __restrict__ Xagg, const unsigned short* __restrict__ Bv,
        const float* __restrict__ wkv_b, const int* __restrict__ off,
        float* __restrict__ agg) {
    __shared__ alignas(16) unsigned short Bs[10752];
    const int t = threadIdx.x, lane = t & 63;
    const int g = blockIdx.x * 4 + (t >> 6);
    const int col = lane & 15, slice = lane >> 4;
    const int row = g * 16 + col;

    short8b af[21];
    {
        const unsigned short* __restrict__ xr = Xagg + (size_t)row * 600;
        #pragma unroll
        for (int kc = 0; kc < 21; ++kc) {
            int j0 = kc * 32 + slice * 8;
            if (j0 + 8 <= 600) {
                af[kc] = *(const short8b*)(xr + j0);
            } else {
                short8b z;
                #pragma unroll
                for (int q = 0; q < 8; ++q) z[q] = 0;
                af[kc] = z;
            }
        }
    }
    f32x4 acc[7];
    #pragma unroll
    for (int nf = 0; nf < 7; ++nf) acc[nf] = (f32x4){0.f, 0.f, 0.f, 0.f};

    #pragma unroll
    for (int slab = 0; slab < 7; ++slab) {
        {
            const float4* __restrict__ ws4 = (const float4*)Bv + (size_t)slab * 1344;
            float4* __restrict__ wd = (float4*)Bs;
            #pragma unroll
            for (int i = 0; i < 5; ++i) wd[i * 256 + t] = ws4[i * 256 + t];
            if (t < 64) wd[1280 + t] = ws4[1280 + t];
        }
        __syncthreads();
        #pragma unroll
        for (int kl = 0; kl < 3; ++kl) {
            const int kc = slab * 3 + kl;
            #pragma unroll
            for (int nf = 0; nf < 7; ++nf) {
                short8b w = *(const short8b*)(&Bs[(size_t)((kl * 7 + nf) * 64 + lane) * 8]);
                acc[nf] = __builtin_amdgcn_mfma_f32_16x16x32_bf16(af[kc], w, acc[nf], 0, 0, 0);
            }
        }
        __syncthreads();
    }
    const int re0 = g * 16 + (slice << 2);
    #pragma unroll
    for (int nf = 0; nf < 7; ++nf) {
        int o = nf * 16 + col;
        if (o < 100) {
            float bv = wkv_b[100 + o];
            #pragma unroll
            for (int r = 0; r < 4; ++r) {
                int node = re0 + r;
                bool has = off[node + 1] > off[node];
                agg[(size_t)node * 100 + o] = acc[nf][r] + (has ? bv : 0.f);
            }
        }
    }
}

// ---------- out proj + relu + layernorm: 8 nodes/block, coalesced wout_t ----------
__global__ __launch_bounds__(128) void k_out(const float* __restrict__ agg,
                                             const float* __restrict__ dst_h,
                                             const float* __restrict__ wout_t,
                                             const float* __restrict__ wout_b,
                                             const float* __restrict__ ln_g,
                                             const float* __restrict__ ln_b,
                                             float* __restrict__ out) {
    __shared__ float Fs[8][200];
    __shared__ float red[8][128];
    const int n0 = blockIdx.x * 8, t = threadIdx.x;
    for (int idx = t; idx < 1600; idx += 128) {
        int n = idx / 200, i = idx % 200;
        Fs[n][i] = (i < 100) ? agg[(size_t)(n0 + n) * 100 + i]
                             : dst_h[(size_t)(n0 + n) * 100 + (i - 100)];
    }
    __syncthreads();
    float v[8] = {0.f, 0.f, 0.f, 0.f, 0.f, 0.f, 0.f, 0.f};
    if (t < 100) {
        float b = wout_b[t];
        #pragma unroll
        for (int n = 0; n < 8; ++n) v[n] = b;
        for (int i = 0; i < 200; ++i) {
            float w = wout_t[i * 100 + t];
            #pragma unroll
            for (int n = 0; n < 8; ++n) v[n] = fmaf(Fs[n][i], w, v[n]);
        }
        #pragma unroll
        for (int n = 0; n < 8; ++n) v[n] = fmaxf(v[n], 0.f);
    }
    #pragma unroll
    for (int n = 0; n < 8; ++n) red[n][t] = (t < 100) ? v[n] : 0.f;
    __syncthreads();
    for (int s = 64; s > 0; s >>= 1) {
        if (t < s) {
            #pragma unroll
            for (int n = 0; n < 8; ++n) red[n][t] += red[n][t + s];
        }
        __syncthreads();
    }
    float mu[8];
    #pragma unroll
    for (int n = 0; n < 8; ++n) mu[n] = red[n][0] * 0.01f;
    __syncthreads();
    #pragma unroll
    for (int n = 0; n < 8; ++n) {
        float dv = (t < 100) ? (v[n] - mu[n]) : 0.f;
        red[n][t] = dv * dv;
    }
    __syncthreads();
    for (int s = 64; s > 0; s >>= 1) {
        if (t < s) {
            #pragma unroll
            for (int n = 0; n < 8; ++n) red[n][t] += red[n][t + s];
        }
        __syncthreads();
    }
    if (t < 100) {
        #pragma unroll
        for (int n = 0; n < 8; ++n) {
            float var = red[n][0] * 0.01f;
            out[(size_t)(n0 + n) * 100 + t] =
                (v[n] - mu[n]) * rsqrtf(var + LN_EPS) * ln_g[t] + ln_b[t];
        }
    }
}

extern "C" void kernel_launch(void* const* d_in, const int* in_sizes, int n_in,
                              void* d_out, int out_size, void* d_ws, size_t ws_size,
                              hipStream_t stream) {
    const float* dst_h   = (const float*)d_in[0];
    const float* src_h   = (const float*)d_in[1];
    const float* efeat   = (const float*)d_in[2];
    const float* td      = (const float*)d_in[3];
    const int*   edst    = (const int*)  d_in[4];
    const float* time_w  = (const float*)d_in[5];
    const float* time_b  = (const float*)d_in[6];
    const float* wq_w    = (const float*)d_in[7];
    const float* wq_b    = (const float*)d_in[8];
    const float* wkv_w   = (const float*)d_in[9];
    const float* wkv_b   = (const float*)d_in[10];
    const float* wout_w  = (const float*)d_in[11];
    const float* wout_b  = (const float*)d_in[12];
    const float* ln_g    = (const float*)d_in[13];
    const float* ln_b    = (const float*)d_in[14];
    float* out = (float*)d_out;

    char* ws = (char*)d_ws;
    size_t off = 0;
    auto carve = [&](size_t bytes) { char* p = ws + off; off = (off + bytes + 255) & ~(size_t)255; return p; };
    unsigned short* QW    = (unsigned short*)carve((size_t)N_DST * 608 * 2);
    unsigned short* Xagg  = (unsigned short*)carve((size_t)N_DST * 600 * 2);
    float*          agg   = (float*)carve((size_t)N_DST * 100 * 4);
    float*          C2    = (float*)carve(602 * 4);
    unsigned short* Bq    = (unsigned short*)carve(77824 * 2);
    unsigned short* Bv    = (unsigned short*)carve(75264 * 2);
    float*          woutT = (float*)carve(20000 * 4);
    float*          zq    = (float*)carve(100 * 4);
    int*            offs  = (int*)carve((size_t)(N_DST + 1) * 4);

    k_prep<<<(95364 + 255) / 256, 256, 0, stream>>>(wkv_w, wq_w, wq_b, time_b, wout_w,
                                                    zq, woutT, Bv);
    k_precomp<<<(78426 + 255) / 256, 256, 0, stream>>>(wq_w, wkv_w, wkv_b, zq, Bq, C2);
    k_offsets<<<(N_DST + 1 + 255) / 256, 256, 0, stream>>>(edst, offs);
    k_qw<<<N_DST / 64, 256, 0, stream>>>(dst_h, Bq, C2, QW);
    k_node<<<N_DST / 4, 256, 0, stream>>>(src_h, efeat, td, time_w, time_b,
                                          QW, offs, Xagg);
    k_aggv<<<N_DST / 64, 256, 0, stream>>>(Xagg, Bv, wkv_b, offs, agg);
    k_out<<<N_DST / 8, 128, 0, stream>>>(agg, dst_h, woutT, wout_b, ln_g, ln_b, out);
}